// Round 2
// 465.049 us; speedup vs baseline: 1.0718x; 1.0718x over previous
//
#include <hip/hip_runtime.h>
#include <stdint.h>

// Problem constants (fixed by the reference):
#define Bq      64
#define Nq      256
#define Hq      8
#define DHq     64
#define TOTALq  16384    // B*N
#define NTq     131072   // H*TOTAL
#define Dq      512      // H*DH

typedef __attribute__((ext_vector_type(8))) short short8;
typedef __attribute__((ext_vector_type(4))) float floatx4;

__device__ __forceinline__ unsigned short f2bf(float f) {
    union { float f; unsigned int u; } c; c.f = f;
    unsigned int u = c.u;
    return (unsigned short)((u + 0x7fffu + ((u >> 16) & 1u)) >> 16);
}
__device__ __forceinline__ float bf2f(unsigned short u) {
    union { unsigned int u; float f; } c; c.u = ((unsigned int)u) << 16;
    return c.f;
}

// ---------------------------------------------------------------------------
// Graph structure: degree -> dinv; dense per-sample P (64 x 256 x 256)
// P[g][d][s] += -(dinv[s]*dinv[d]) per edge (handles duplicates like segment_sum)
// ---------------------------------------------------------------------------

__global__ void count_deg_kernel(const int* __restrict__ dstp, int* __restrict__ cnt, int E) {
    int e = blockIdx.x * 256 + threadIdx.x;
    if (e < E) atomicAdd(&cnt[dstp[e]], 1);
}

__global__ void dinv_kernel(const int* __restrict__ cnt, float* __restrict__ dinv_n) {
    int v = blockIdx.x * 256 + threadIdx.x;
    if (v < TOTALq) {
        int c = cnt[v];
        dinv_n[v] = (c > 0) ? rsqrtf((float)c) : 0.0f;
    }
}

__global__ void pscatter_kernel(const int* __restrict__ srcp, const int* __restrict__ dstp,
                                const float* __restrict__ dinv_n, float* __restrict__ Pf, int E) {
    int e = blockIdx.x * 256 + threadIdx.x;
    if (e >= E) return;
    int s = srcp[e], d = dstp[e];
    int g = d >> 8;  // sample index (s and d are in the same sample by construction)
    atomicAdd(&Pf[((size_t)g << 16) + ((size_t)(d & 255) << 8) + (s & 255)],
              -(dinv_n[s] * dinv_n[d]));
}

__global__ void pconv_kernel(const float* __restrict__ Pf, unsigned short* __restrict__ Pb) {
    int i = (blockIdx.x * 256 + threadIdx.x) * 4;
    float4 v = *(const float4*)(Pf + i);
    unsigned int lo = (unsigned int)f2bf(v.x) | ((unsigned int)f2bf(v.y) << 16);
    unsigned int hi = (unsigned int)f2bf(v.z) | ((unsigned int)f2bf(v.w) << 16);
    *(uint2*)(Pb + i) = make_uint2(lo, hi);
}

// ---------------------------------------------------------------------------
// oeh (16384 x 512 fp32, col = h*64+dh) -> X0_t (512 x 16384 bf16), transposed
// grid (256, 8), 64x64 tiles
// ---------------------------------------------------------------------------
__global__ void x0t_kernel(const float* __restrict__ X, unsigned short* __restrict__ Xt) {
    __shared__ float tile[64 * 68];
    int t = threadIdx.x;
    int n0 = blockIdx.x * 64, c0 = blockIdx.y * 64;
#pragma unroll
    for (int it = 0; it < 4; ++it) {
        int idx = it * 256 + t;
        int nr = idx >> 4, sub = idx & 15;
        float4 v = *(const float4*)(X + (size_t)(n0 + nr) * 512 + c0 + sub * 4);
        *(float4*)(&tile[nr * 68 + sub * 4]) = v;
    }
    __syncthreads();
#pragma unroll
    for (int it = 0; it < 2; ++it) {
        int idx = it * 256 + t;
        int cr = idx >> 3, sub = idx & 7;
        unsigned int pk[4];
#pragma unroll
        for (int q = 0; q < 4; ++q) {
            unsigned short a = f2bf(tile[(sub * 8 + q * 2 + 0) * 68 + cr]);
            unsigned short b = f2bf(tile[(sub * 8 + q * 2 + 1) * 68 + cr]);
            pk[q] = (unsigned int)a | ((unsigned int)b << 16);
        }
        *(uint4*)(Xt + (size_t)(c0 + cr) * 16384 + n0 + sub * 8) =
            make_uint4(pk[0], pk[1], pk[2], pk[3]);
    }
}

// bf16 transpose: Tt (512 x 16384) -> Tn (16384 x 512). grid (256, 8)
__global__ void trn_kernel(const unsigned short* __restrict__ Tt, unsigned short* __restrict__ Tn) {
    __shared__ unsigned short tile[64 * 72];
    int t = threadIdx.x;
    int n0 = blockIdx.x * 64, c0 = blockIdx.y * 64;
#pragma unroll
    for (int it = 0; it < 2; ++it) {
        int idx = it * 256 + t;
        int cr = idx >> 3, sub = idx & 7;
        uint4 v = *(const uint4*)(Tt + (size_t)(c0 + cr) * 16384 + n0 + sub * 8);
        *(uint4*)(&tile[cr * 72 + sub * 8]) = v;
    }
    __syncthreads();
#pragma unroll
    for (int it = 0; it < 2; ++it) {
        int idx = it * 256 + t;
        int nr = idx >> 3, sub = idx & 7;
        unsigned int pk[4];
#pragma unroll
        for (int q = 0; q < 4; ++q) {
            unsigned short a = tile[(sub * 8 + q * 2 + 0) * 72 + nr];
            unsigned short b = tile[(sub * 8 + q * 2 + 1) * 72 + nr];
            pk[q] = (unsigned int)a | ((unsigned int)b << 16);
        }
        *(uint4*)(Tn + (size_t)(n0 + nr) * 512 + c0 + sub * 8) =
            make_uint4(pk[0], pk[1], pk[2], pk[3]);
    }
}

// W_cheb (4 x 64 x 64, [k][j][n]) -> WchT bf16 [k][n][j]
__global__ void wchebt_kernel(const float* __restrict__ W, unsigned short* __restrict__ WT) {
    int idx = blockIdx.x * 256 + threadIdx.x;  // 16384 total
    int k = idx >> 12, rem = idx & 4095;
    int n = rem >> 6, j = rem & 63;
    WT[idx] = f2bf(W[(k << 12) + (j << 6) + n]);
}

// ---------------------------------------------------------------------------
// Coefficient kernel: one block per graph g = h*B + b (512 blocks, 256 thr)
// ---------------------------------------------------------------------------
__global__ void coeff_kernel(const float* __restrict__ attn,
                             const float* __restrict__ Wg, const float* __restrict__ bg,
                             const float* __restrict__ Wlin, const float* __restrict__ blin,
                             float* __restrict__ coeff) {
    __shared__ float dinv[Nq];
    __shared__ float red[16];
    int g = blockIdx.x;
    int h = g >> 6;
    int b = g & 63;
    const float* A = attn + ((size_t)(b * Hq + h)) * (Nq * Nq);
    int j = threadIdx.x;

    float cs = 0.0f;
    for (int i = 0; i < Nq; ++i) cs += A[i * Nq + j];
    float dv = rsqrtf(cs + 1.0f);
    dinv[j] = dv;
    __syncthreads();

    float sj = dv;
    for (int i = 0; i < Nq; ++i) sj += dinv[i] * A[i * Nq + j];
    sj *= dv;

    float xc[4];
#pragma unroll
    for (int c = 0; c < 4; ++c) {
        float wr = Wg[0 * 4 + c] + Wg[1 * 4 + c] + Wg[2 * 4 + c] + Wg[3 * 4 + c];
        xc[c] = tanhf(sj * wr + bg[c]);
    }
    int lane = j & 63, wv = j >> 6;
#pragma unroll
    for (int c = 0; c < 4; ++c) {
        float v = xc[c];
#pragma unroll
        for (int o = 32; o >= 1; o >>= 1) v += __shfl_down(v, o, 64);
        if (lane == 0) red[wv * 4 + c] = v;
    }
    __syncthreads();
    if (j < 4) {
        float gap[4];
#pragma unroll
        for (int c = 0; c < 4; ++c)
            gap[c] = (red[0 + c] + red[4 + c] + red[8 + c] + red[12 + c]) * (1.0f / 256.0f);
        float v = blin[j];
#pragma unroll
        for (int c = 0; c < 4; ++c) v += gap[c] * Wlin[c * 4 + j];
        coeff[g * 4 + j] = v;
    }
}

// ---------------------------------------------------------------------------
// Chebyshev propagation via per-sample dense MFMA GEMM.
// Tn_t[col][node] = first ? (P_b @ Tc)  :  2*(P_b @ Tc) - Tp
// grid (64 samples, 2 row-halves, 4 col-blocks); 256 thr; BM=128,BN=128,BK=32
// ---------------------------------------------------------------------------
__global__ __launch_bounds__(256, 2)
void cheb_prop(const unsigned short* __restrict__ Pb,
               const unsigned short* __restrict__ Tc,
               const unsigned short* __restrict__ Tp,
               unsigned short* __restrict__ Tn, int first) {
    __shared__ unsigned short A_lds[128 * 40];
    __shared__ unsigned short B_lds[128 * 40];
    const int b = blockIdx.x, mb = blockIdx.y, cb = blockIdx.z;
    const int tid = threadIdx.x, lane = tid & 63, wv = tid >> 6;
    const int wr = wv & 1, wc = wv >> 1, quad = lane >> 4, l15 = lane & 15;
    const unsigned short* Pbase = Pb + ((size_t)b << 16) + (size_t)mb * 128 * 256;

    floatx4 acc[4][4];
#pragma unroll
    for (int rt = 0; rt < 4; ++rt)
#pragma unroll
        for (int ct = 0; ct < 4; ++ct) acc[rt][ct] = (floatx4){0.f, 0.f, 0.f, 0.f};

    for (int kt = 0; kt < 8; ++kt) {
        const int kc = kt * 32;
        __syncthreads();
#pragma unroll
        for (int it = 0; it < 2; ++it) {
            int idx = it * 256 + tid;
            int row = idx >> 2, sub = idx & 3;
            *(uint4*)(A_lds + row * 40 + sub * 8) =
                *(const uint4*)(Pbase + row * 256 + kc + sub * 8);
            *(uint4*)(B_lds + row * 40 + sub * 8) =
                *(const uint4*)(Tc + (size_t)(cb * 128 + row) * 16384 + b * 256 + kc + sub * 8);
        }
        __syncthreads();
        short8 af[4], bfr[4];
#pragma unroll
        for (int rt = 0; rt < 4; ++rt)
            af[rt] = *(const short8*)(A_lds + (wr * 64 + rt * 16 + l15) * 40 + quad * 8);
#pragma unroll
        for (int ct = 0; ct < 4; ++ct)
            bfr[ct] = *(const short8*)(B_lds + (wc * 64 + ct * 16 + l15) * 40 + quad * 8);
#pragma unroll
        for (int rt = 0; rt < 4; ++rt)
#pragma unroll
            for (int ct = 0; ct < 4; ++ct)
                acc[rt][ct] = __builtin_amdgcn_mfma_f32_16x16x32_bf16(af[rt], bfr[ct],
                                                                     acc[rt][ct], 0, 0, 0);
    }
#pragma unroll
    for (int rt = 0; rt < 4; ++rt)
#pragma unroll
        for (int ct = 0; ct < 4; ++ct) {
            int col = cb * 128 + wc * 64 + ct * 16 + l15;
            int m = mb * 128 + wr * 64 + rt * 16 + quad * 4;
            size_t base = (size_t)col * 16384 + b * 256 + m;
            float v[4];
            if (first) {
#pragma unroll
                for (int i = 0; i < 4; ++i) v[i] = acc[rt][ct][i];
            } else {
                uint2 tp = *(const uint2*)(Tp + base);
                v[0] = 2.0f * acc[rt][ct][0] - bf2f((unsigned short)(tp.x & 0xffff));
                v[1] = 2.0f * acc[rt][ct][1] - bf2f((unsigned short)(tp.x >> 16));
                v[2] = 2.0f * acc[rt][ct][2] - bf2f((unsigned short)(tp.y & 0xffff));
                v[3] = 2.0f * acc[rt][ct][3] - bf2f((unsigned short)(tp.y >> 16));
            }
            unsigned int lo = (unsigned int)f2bf(v[0]) | ((unsigned int)f2bf(v[1]) << 16);
            unsigned int hi = (unsigned int)f2bf(v[2]) | ((unsigned int)f2bf(v[3]) << 16);
            *(uint2*)(Tn + base) = make_uint2(lo, hi);
        }
}

// ---------------------------------------------------------------------------
// filtb[(n*B+b)*512 + h*64 + c] = bf16( b_cheb[c] + sum_k ck(h,b) * (T_k @ W_cheb[k]) )
// grid (64 samples, 8 heads); 256 thr. A = ck*T_k (256x64), B = W_k^T (64x64)
// ---------------------------------------------------------------------------
__global__ __launch_bounds__(256, 2)
void filt_kernel(const float* __restrict__ oeh,
                 const unsigned short* __restrict__ T1n, const unsigned short* __restrict__ T2n,
                 const unsigned short* __restrict__ T3n, const unsigned short* __restrict__ WchT,
                 const float* __restrict__ coeff, const float* __restrict__ bch,
                 unsigned short* __restrict__ filtb) {
    __shared__ unsigned short A_lds[256 * 72];  // 36 KB
    __shared__ unsigned short W_lds[64 * 72];   // 9 KB
    const int b = blockIdx.x, h = blockIdx.y;
    const int tid = threadIdx.x, lane = tid & 63, wv = tid >> 6;
    const int quad = lane >> 4, l15 = lane & 15;

    floatx4 acc[4][4];
#pragma unroll
    for (int rt = 0; rt < 4; ++rt)
#pragma unroll
        for (int ct = 0; ct < 4; ++ct) acc[rt][ct] = (floatx4){0.f, 0.f, 0.f, 0.f};

    for (int k = 0; k < 4; ++k) {
        float ck = coeff[(h * Bq + b) * 4 + k];
        __syncthreads();
        if (k == 0) {
#pragma unroll
            for (int it = 0; it < 8; ++it) {
                int idx = it * 256 + tid;
                int row = idx >> 3, sub = idx & 7;
                const float* sp = oeh + (size_t)(b * 256 + row) * 512 + h * 64 + sub * 8;
                float4 v0 = *(const float4*)sp;
                float4 v1 = *(const float4*)(sp + 4);
                unsigned int p0 = (unsigned int)f2bf(v0.x * ck) | ((unsigned int)f2bf(v0.y * ck) << 16);
                unsigned int p1 = (unsigned int)f2bf(v0.z * ck) | ((unsigned int)f2bf(v0.w * ck) << 16);
                unsigned int p2 = (unsigned int)f2bf(v1.x * ck) | ((unsigned int)f2bf(v1.y * ck) << 16);
                unsigned int p3 = (unsigned int)f2bf(v1.z * ck) | ((unsigned int)f2bf(v1.w * ck) << 16);
                *(uint4*)(A_lds + row * 72 + sub * 8) = make_uint4(p0, p1, p2, p3);
            }
        } else {
            const unsigned short* Tk = (k == 1) ? T1n : (k == 2) ? T2n : T3n;
#pragma unroll
            for (int it = 0; it < 8; ++it) {
                int idx = it * 256 + tid;
                int row = idx >> 3, sub = idx & 7;
                uint4 tv = *(const uint4*)(Tk + (size_t)(b * 256 + row) * 512 + h * 64 + sub * 8);
                unsigned int w[4] = {tv.x, tv.y, tv.z, tv.w};
                unsigned int o[4];
#pragma unroll
                for (int q = 0; q < 4; ++q) {
                    float lo = bf2f((unsigned short)(w[q] & 0xffff)) * ck;
                    float hi = bf2f((unsigned short)(w[q] >> 16)) * ck;
                    o[q] = (unsigned int)f2bf(lo) | ((unsigned int)f2bf(hi) << 16);
                }
                *(uint4*)(A_lds + row * 72 + sub * 8) = make_uint4(o[0], o[1], o[2], o[3]);
            }
        }
#pragma unroll
        for (int it = 0; it < 2; ++it) {
            int idx = it * 256 + tid;
            int r = idx >> 3, sub = idx & 7;
            *(uint4*)(W_lds + r * 72 + sub * 8) =
                *(const uint4*)(WchT + k * 4096 + r * 64 + sub * 8);
        }
        __syncthreads();
#pragma unroll
        for (int kk = 0; kk < 2; ++kk) {
            short8 af[4], bfr[4];
#pragma unroll
            for (int rt = 0; rt < 4; ++rt)
                af[rt] = *(const short8*)(A_lds + (wv * 64 + rt * 16 + l15) * 72 + kk * 32 + quad * 8);
#pragma unroll
            for (int ct = 0; ct < 4; ++ct)
                bfr[ct] = *(const short8*)(W_lds + (ct * 16 + l15) * 72 + kk * 32 + quad * 8);
#pragma unroll
            for (int rt = 0; rt < 4; ++rt)
#pragma unroll
                for (int ct = 0; ct < 4; ++ct)
                    acc[rt][ct] = __builtin_amdgcn_mfma_f32_16x16x32_bf16(af[rt], bfr[ct],
                                                                         acc[rt][ct], 0, 0, 0);
        }
    }
#pragma unroll
    for (int rt = 0; rt < 4; ++rt)
#pragma unroll
        for (int ct = 0; ct < 4; ++ct) {
            int coln = ct * 16 + l15;
            float bias = bch[coln];
#pragma unroll
            for (int i = 0; i < 4; ++i) {
                int m = wv * 64 + rt * 16 + quad * 4 + i;  // local node n
                size_t r = (size_t)m * 64 + b;             // n*B + b
                filtb[r * 512 + h * 64 + coln] = f2bf(acc[rt][ct][i] + bias);
            }
        }
}

// ---------------------------------------------------------------------------
// W_cat (1024 x 512 fp32, [k][col]) -> Wt2 bf16 in MFMA-fragment order:
//   Wt2[((kt*4 + q)*512 + col)*8 + e] = bf16(W_cat[(kt*32 + q*8 + e)*512 + col])
// so a wave's B fragment for (kt, quad, col-range) is a contiguous 16B chunk.
// 65536 chunks, one per thread; reads coalesced (64 consecutive cols per lane).
// ---------------------------------------------------------------------------
__global__ void wt2_kernel(const float* __restrict__ W, unsigned short* __restrict__ Wt2) {
    int idx = blockIdx.x * 256 + threadIdx.x;   // 0..65535
    int col = idx & 511;
    int ktq = idx >> 9;                         // 0..127 ; k base = ktq*8
    const float* src = W + (size_t)(ktq * 8) * 512 + col;
    unsigned int pk[4];
#pragma unroll
    for (int q2 = 0; q2 < 4; ++q2) {
        unsigned short a = f2bf(src[(q2 * 2 + 0) * 512]);
        unsigned short b = f2bf(src[(q2 * 2 + 1) * 512]);
        pk[q2] = (unsigned int)a | ((unsigned int)b << 16);
    }
    *(uint4*)(Wt2 + (size_t)idx * 8) = make_uint4(pk[0], pk[1], pk[2], pk[3]);
}

// ---------------------------------------------------------------------------
// MFMA GEMM (M=16384, K=1024, N=512) + fused LayerNorm.
// 512 threads = 8 waves, per-wave tile 64(M) x 64(N); grid 256 = M/64.
// B: direct global->reg double-buffer from Wt2 (fragment-ordered, never in LDS).
// A: LDS double-buffer [kquad][row64][8], staged with early-issued loads so the
//    single per-kt __syncthreads vmcnt(0) drain lands after the MFMA cluster.
// Epilogue: fp32 row cache in LDS (overlays A buffers) + wave-parallel LN.
// ---------------------------------------------------------------------------
__global__ __launch_bounds__(512, 2)
void gemm_ln_mfma(const float* __restrict__ outp, const unsigned short* __restrict__ filtb,
                  const unsigned short* __restrict__ Wt2, const float* __restrict__ bcat,
                  const float* __restrict__ gamma, const float* __restrict__ beta,
                  float* __restrict__ out) {
    extern __shared__ unsigned char smc[];
    unsigned short* A_lds0 = (unsigned short*)smc;           // 4 KB  [q][row][8]
    unsigned short* A_lds1 = (unsigned short*)(smc + 4096);  // 4 KB  (double buffer)
    float* ep = (float*)smc;                                 // 64 KB epilogue overlay

    const int tid = threadIdx.x;
    const int lane = tid & 63;
    const int wv = tid >> 6;          // 0..7  (N-quadrant: cols wv*64..wv*64+63)
    const int quad = lane >> 4;       // k-group within fragment
    const int l15 = lane & 15;
    const int r0 = blockIdx.x * 64;

    // A staging assignment: thread -> (row, 4 consecutive k)
    const int s_row = tid >> 3;       // 0..63
    const int s_sub = tid & 7;        // k-offset = s_sub*4
    const int s_q   = s_sub >> 1;
    const int s_e   = (s_sub & 1) * 4;

    const size_t boff = (size_t)(quad * 512 + wv * 64 + l15) * 8;  // B fragment base (shorts)

    floatx4 acc[4][4];
#pragma unroll
    for (int rt = 0; rt < 4; ++rt)
#pragma unroll
        for (int ct = 0; ct < 4; ++ct) acc[rt][ct] = (floatx4){0.f, 0.f, 0.f, 0.f};

    short8 bA[4], bB[4];

    // Prologue: B fragments for kt=0 + A tile 0 into A_lds0.
    {
#pragma unroll
        for (int ct = 0; ct < 4; ++ct)
            bA[ct] = *(const short8*)(Wt2 + boff + ct * 128);
        float4 av = *(const float4*)(outp + (size_t)(r0 + s_row) * 512 + s_sub * 4);
        uint2 ap;
        ap.x = (unsigned int)f2bf(av.x) | ((unsigned int)f2bf(av.y) << 16);
        ap.y = (unsigned int)f2bf(av.z) | ((unsigned int)f2bf(av.w) << 16);
        *(uint2*)(A_lds0 + (s_q * 64 + s_row) * 8 + s_e) = ap;
        __syncthreads();
    }

// One K-step: prefetch (B regs + A regs) for KT+1, compute KT, barrier, commit A.
#define GSTEP(KT, BC, BN, AC, AN, HASNEXT)                                          \
    do {                                                                            \
        const int kt_ = (KT);                                                       \
        const bool hn_ = (HASNEXT);                                                 \
        const bool isf_ = (kt_ + 1 < 16);                                           \
        float4 av_; uint2 afb_;                                                     \
        if (hn_) {                                                                  \
            _Pragma("unroll")                                                       \
            for (int ct = 0; ct < 4; ++ct)                                          \
                BN[ct] = *(const short8*)(Wt2 + (size_t)(kt_ + 1) * 16384 +         \
                                          boff + ct * 128);                         \
            const int kc_ = (kt_ + 1) * 32;                                         \
            if (isf_)                                                               \
                av_ = *(const float4*)(outp + (size_t)(r0 + s_row) * 512 +          \
                                       kc_ + s_sub * 4);                            \
            else                                                                    \
                afb_ = *(const uint2*)(filtb + (size_t)(r0 + s_row) * 512 +         \
                                       (kc_ - 512) + s_sub * 4);                    \
        }                                                                           \
        short8 af_[4];                                                              \
        _Pragma("unroll")                                                           \
        for (int rt = 0; rt < 4; ++rt)                                              \
            af_[rt] = *(const short8*)(AC + (quad * 64 + rt * 16 + l15) * 8);       \
        _Pragma("unroll")                                                           \
        for (int rt = 0; rt < 4; ++rt)                                              \
            _Pragma("unroll")                                                       \
            for (int ct = 0; ct < 4; ++ct)                                          \
                acc[rt][ct] = __builtin_amdgcn_mfma_f32_16x16x32_bf16(              \
                    af_[rt], BC[ct], acc[rt][ct], 0, 0, 0);                         \
        if (hn_) {                                                                  \
            uint2 ap_;                                                              \
            if (isf_) {                                                             \
                ap_.x = (unsigned int)f2bf(av_.x) | ((unsigned int)f2bf(av_.y) << 16); \
                ap_.y = (unsigned int)f2bf(av_.z) | ((unsigned int)f2bf(av_.w) << 16); \
            } else {                                                                \
                ap_ = afb_;                                                         \
            }                                                                       \
            *(uint2*)(AN + (s_q * 64 + s_row) * 8 + s_e) = ap_;                     \
        }                                                                           \
        __syncthreads();                                                            \
    } while (0)

    for (int kt2 = 0; kt2 < 16; ++kt2) {
        GSTEP(2 * kt2,     bA, bB, A_lds0, A_lds1, true);
        GSTEP(2 * kt2 + 1, bB, bA, A_lds1, A_lds0, kt2 < 15);
    }
#undef GSTEP

    // ---------------- fused LayerNorm epilogue ----------------
    float gg[8], bb[8];
#pragma unroll
    for (int i = 0; i < 8; ++i) { gg[i] = gamma[i * 64 + lane]; bb[i] = beta[i * 64 + lane]; }
    float bc[4];
#pragma unroll
    for (int ct = 0; ct < 4; ++ct) bc[ct] = bcat[wv * 64 + ct * 16 + l15];

    for (int half = 0; half < 2; ++half) {
        __syncthreads();
#pragma unroll
        for (int rt2 = 0; rt2 < 2; ++rt2) {
            const int rt = half * 2 + rt2;
#pragma unroll
            for (int ct = 0; ct < 4; ++ct) {
                const int col = wv * 64 + ct * 16 + l15;
#pragma unroll
                for (int i = 0; i < 4; ++i) {
                    const int row_l = rt2 * 16 + quad * 4 + i;
                    ep[row_l * 512 + col] = acc[rt][ct][i] + bc[ct];
                }
            }
        }
        __syncthreads();
#pragma unroll
        for (int m4 = 0; m4 < 4; ++m4) {
            const int m = wv * 4 + m4;
            float s = 0.0f, ss = 0.0f;
#pragma unroll
            for (int i = 0; i < 8; ++i) {
                float v = ep[m * 512 + i * 64 + lane];
                s += v; ss += v * v;
            }
#pragma unroll
            for (int o = 32; o >= 1; o >>= 1) {
                s += __shfl_down(s, o, 64);
                ss += __shfl_down(ss, o, 64);
            }
            s = __shfl(s, 0, 64);
            ss = __shfl(ss, 0, 64);
            const float mu = s * (1.0f / 512.0f);
            const float var = ss * (1.0f / 512.0f) - mu * mu;
            const float rs = rsqrtf(var + 1e-5f);
            const int r = r0 + half * 32 + m;
#pragma unroll
            for (int i = 0; i < 8; ++i) {
                const int d = i * 64 + lane;
                out[(size_t)r * 512 + d] = (ep[m * 512 + d] - mu) * rs * gg[i] + bb[i];
            }
        }
    }
}

// ---------------------------------------------------------------------------
// Launch
// ---------------------------------------------------------------------------
extern "C" void kernel_launch(void* const* d_in, const int* in_sizes, int n_in,
                              void* d_out, int out_size, void* d_ws, size_t ws_size,
                              hipStream_t stream) {
    const float* output       = (const float*)d_in[0];
    const float* attn         = (const float*)d_in[1];
    const float* oeh          = (const float*)d_in[2];
    const int*   edge_index   = (const int*)d_in[3];
    const float* W_gcn        = (const float*)d_in[6];
    const float* b_gcn        = (const float*)d_in[7];
    const float* W_lin        = (const float*)d_in[8];
    const float* b_lin        = (const float*)d_in[9];
    const float* W_cheb       = (const float*)d_in[10];
    const float* b_cheb       = (const float*)d_in[11];
    const float* W_cat        = (const float*)d_in[12];
    const float* b_cat        = (const float*)d_in[13];
    const float* gamma        = (const float*)d_in[14];
    const float* beta         = (const float*)d_in[15];
    float* out = (float*)d_out;

    const int E = in_sizes[3] / 2;
    const int* srcp = edge_index;
    const int* dstp = edge_index + E;

    uint8_t* ws = (uint8_t*)d_ws;
    size_t cur = 0;
    auto alloc = [&](size_t bytes) -> void* {
        void* p = ws + cur;
        cur += (bytes + 255) & ~(size_t)255;
        return p;
    };
    int*   cnt     = (int*)alloc(TOTALq * sizeof(int));
    float* dinv_n  = (float*)alloc(TOTALq * sizeof(float));
    float* Pf      = (float*)alloc((size_t)64 * 65536 * sizeof(float));     // 16.8 MB
    unsigned short* Pb   = (unsigned short*)alloc((size_t)64 * 65536 * 2);  //  8.4 MB
    float* coeff   = (float*)alloc(512 * 4 * sizeof(float));
    unsigned short* X0_t = (unsigned short*)alloc((size_t)512 * 16384 * 2); // 16.8 MB
    unsigned short* T1_t = (unsigned short*)alloc((size_t)512 * 16384 * 2);
    unsigned short* T2_t = (unsigned short*)alloc((size_t)512 * 16384 * 2);
    unsigned short* T3_t = (unsigned short*)alloc((size_t)512 * 16384 * 2);
    unsigned short* WchT = (unsigned short*)alloc(4 * 64 * 64 * 2);
    unsigned short* Wt2  = (unsigned short*)alloc((size_t)Dq * 1024 * 2);
    unsigned short* filtb = (unsigned short*)alloc((size_t)TOTALq * Dq * sizeof(float)); // over-alloc ok
    // aliases into dead regions (lifetimes verified by launch order):
    unsigned short* T1_n = (unsigned short*)Pf;   // Pf dead after pconv
    unsigned short* T2_n = X0_t;                  // X0_t dead after prop2
    unsigned short* T3_n = T1_t;                  // T1_t dead after prop3+trn1
    (void)ws_size; (void)n_in; (void)out_size;

    hipMemsetAsync(cnt, 0, TOTALq * sizeof(int), stream);
    count_deg_kernel<<<(E + 255) / 256, 256, 0, stream>>>(dstp, cnt, E);
    dinv_kernel<<<TOTALq / 256, 256, 0, stream>>>(cnt, dinv_n);
    hipMemsetAsync(Pf, 0, (size_t)64 * 65536 * sizeof(float), stream);
    pscatter_kernel<<<(E + 255) / 256, 256, 0, stream>>>(srcp, dstp, dinv_n, Pf, E);
    pconv_kernel<<<4096, 256, 0, stream>>>(Pf, Pb);

    x0t_kernel<<<dim3(256, 8), 256, 0, stream>>>(oeh, X0_t);
    coeff_kernel<<<Hq * Bq, 256, 0, stream>>>(attn, W_gcn, b_gcn, W_lin, b_lin, coeff);
    wt2_kernel<<<256, 256, 0, stream>>>(W_cat, Wt2);
    wchebt_kernel<<<64, 256, 0, stream>>>(W_cheb, WchT);

    dim3 pg(64, 2, 4);
    cheb_prop<<<pg, 256, 0, stream>>>(Pb, X0_t, nullptr, T1_t, 1);
    cheb_prop<<<pg, 256, 0, stream>>>(Pb, T1_t, X0_t, T2_t, 0);
    cheb_prop<<<pg, 256, 0, stream>>>(Pb, T2_t, T1_t, T3_t, 0);

    trn_kernel<<<dim3(256, 8), 256, 0, stream>>>(T1_t, T1_n);
    trn_kernel<<<dim3(256, 8), 256, 0, stream>>>(T2_t, T2_n);
    trn_kernel<<<dim3(256, 8), 256, 0, stream>>>(T3_t, T3_n);  // writes over T1_t (already consumed)

    filt_kernel<<<dim3(64, 8), 256, 0, stream>>>(oeh, T1_n, T2_n, T3_n, WchT, coeff,
                                                 b_cheb, filtb);

    gemm_ln_mfma<<<TOTALq / 64, 512, 65536, stream>>>(output, filtb, Wt2, b_cat,
                                                      gamma, beta, out);
}

// Round 3
// 437.005 us; speedup vs baseline: 1.1406x; 1.0642x over previous
//
#include <hip/hip_runtime.h>
#include <stdint.h>

// Problem constants (fixed by the reference):
#define Bq      64
#define Nq      256
#define Hq      8
#define DHq     64
#define TOTALq  16384    // B*N
#define NTq     131072   // H*TOTAL
#define Dq      512      // H*DH

typedef __attribute__((ext_vector_type(8))) short short8;
typedef __attribute__((ext_vector_type(4))) float floatx4;

__device__ __forceinline__ unsigned short f2bf(float f) {
    union { float f; unsigned int u; } c; c.f = f;
    unsigned int u = c.u;
    return (unsigned short)((u + 0x7fffu + ((u >> 16) & 1u)) >> 16);
}
__device__ __forceinline__ float bf2f(unsigned short u) {
    union { unsigned int u; float f; } c; c.u = ((unsigned int)u) << 16;
    return c.f;
}

// ---------------------------------------------------------------------------
// Graph structure: degree -> dinv; dense per-sample P (64 x 256 x 256)
// ---------------------------------------------------------------------------

__global__ void count_deg_kernel(const int* __restrict__ dstp, int* __restrict__ cnt, int E) {
    int e = blockIdx.x * 256 + threadIdx.x;
    if (e < E) atomicAdd(&cnt[dstp[e]], 1);
}

__global__ void dinv_kernel(const int* __restrict__ cnt, float* __restrict__ dinv_n) {
    int v = blockIdx.x * 256 + threadIdx.x;
    if (v < TOTALq) {
        int c = cnt[v];
        dinv_n[v] = (c > 0) ? rsqrtf((float)c) : 0.0f;
    }
}

__global__ void pscatter_kernel(const int* __restrict__ srcp, const int* __restrict__ dstp,
                                const float* __restrict__ dinv_n, float* __restrict__ Pf, int E) {
    int e = blockIdx.x * 256 + threadIdx.x;
    if (e >= E) return;
    int s = srcp[e], d = dstp[e];
    int g = d >> 8;  // sample index
    atomicAdd(&Pf[((size_t)g << 16) + ((size_t)(d & 255) << 8) + (s & 255)],
              -(dinv_n[s] * dinv_n[d]));
}

__global__ void pconv_kernel(const float* __restrict__ Pf, unsigned short* __restrict__ Pb) {
    int i = (blockIdx.x * 256 + threadIdx.x) * 4;
    float4 v = *(const float4*)(Pf + i);
    unsigned int lo = (unsigned int)f2bf(v.x) | ((unsigned int)f2bf(v.y) << 16);
    unsigned int hi = (unsigned int)f2bf(v.z) | ((unsigned int)f2bf(v.w) << 16);
    *(uint2*)(Pb + i) = make_uint2(lo, hi);
}

// ---------------------------------------------------------------------------
// oeh (16384 x 512 fp32) -> X0_t (512 x 16384 bf16), transposed. grid (256, 8)
// ---------------------------------------------------------------------------
__global__ void x0t_kernel(const float* __restrict__ X, unsigned short* __restrict__ Xt) {
    __shared__ float tile[64 * 68];
    int t = threadIdx.x;
    int n0 = blockIdx.x * 64, c0 = blockIdx.y * 64;
#pragma unroll
    for (int it = 0; it < 4; ++it) {
        int idx = it * 256 + t;
        int nr = idx >> 4, sub = idx & 15;
        float4 v = *(const float4*)(X + (size_t)(n0 + nr) * 512 + c0 + sub * 4);
        *(float4*)(&tile[nr * 68 + sub * 4]) = v;
    }
    __syncthreads();
#pragma unroll
    for (int it = 0; it < 2; ++it) {
        int idx = it * 256 + t;
        int cr = idx >> 3, sub = idx & 7;
        unsigned int pk[4];
#pragma unroll
        for (int q = 0; q < 4; ++q) {
            unsigned short a = f2bf(tile[(sub * 8 + q * 2 + 0) * 68 + cr]);
            unsigned short b = f2bf(tile[(sub * 8 + q * 2 + 1) * 68 + cr]);
            pk[q] = (unsigned int)a | ((unsigned int)b << 16);
        }
        *(uint4*)(Xt + (size_t)(c0 + cr) * 16384 + n0 + sub * 8) =
            make_uint4(pk[0], pk[1], pk[2], pk[3]);
    }
}

// W_cheb (4 x 64 x 64, [k][j][n]) -> WchTf fp32 [k][n][j]  (scaled+bf16'd in filt)
__global__ void wchebt_kernel(const float* __restrict__ W, float* __restrict__ WT) {
    int idx = blockIdx.x * 256 + threadIdx.x;  // 16384 total
    int k = idx >> 12, rem = idx & 4095;
    int n = rem >> 6, j = rem & 63;
    WT[idx] = W[(k << 12) + (j << 6) + n];
}

// ---------------------------------------------------------------------------
// Coefficient kernel v2: one block per graph g = h*B + b; 512 thr, float4 cols.
// Pass1: colsum -> dinv. Pass2: weighted colsum -> s_j -> tanh -> gap -> coeff.
// ---------------------------------------------------------------------------
__global__ __launch_bounds__(512)
void coeff_kernel(const float* __restrict__ attn,
                  const float* __restrict__ Wg, const float* __restrict__ bg,
                  const float* __restrict__ Wlin, const float* __restrict__ blin,
                  float* __restrict__ coeff) {
    __shared__ floatx4 part[8][64];   // 8 KB
    __shared__ floatx4 dinv4[64];     // 1 KB (256 dinv values)
    const int g = blockIdx.x;
    const int h = g >> 6;
    const int b = g & 63;
    const float* A = attn + ((size_t)(b * Hq + h)) * (Nq * Nq);
    const int tid = threadIdx.x;
    const int rg = tid >> 6;          // 8 row groups of 32 rows
    const int cv = tid & 63;          // float4 column group
    const float* Ap = A + cv * 4;

    floatx4 s1 = (floatx4){0.f, 0.f, 0.f, 0.f};
#pragma unroll 8
    for (int r = 0; r < 32; ++r)
        s1 += *(const floatx4*)(Ap + (size_t)(rg * 32 + r) * 256);
    part[rg][cv] = s1;
    __syncthreads();

    if (tid < 64) {
        floatx4 cs = part[0][tid];
#pragma unroll
        for (int i = 1; i < 8; ++i) cs += part[i][tid];
        floatx4 dv;
#pragma unroll
        for (int i = 0; i < 4; ++i) dv[i] = rsqrtf(cs[i] + 1.0f);
        dinv4[tid] = dv;
    }
    __syncthreads();

    const float* dsc = (const float*)dinv4;
    floatx4 s2 = (floatx4){0.f, 0.f, 0.f, 0.f};
#pragma unroll 8
    for (int r = 0; r < 32; ++r) {
        int rr = rg * 32 + r;
        s2 += dsc[rr] * (*(const floatx4*)(Ap + (size_t)rr * 256));
    }
    part[rg][cv] = s2;
    __syncthreads();

    if (tid < 64) {
        floatx4 ws = part[0][tid];
#pragma unroll
        for (int i = 1; i < 8; ++i) ws += part[i][tid];
        floatx4 dv = dinv4[tid];
        floatx4 sj = (ws + dv) * dv;

        float wr[4], bgl[4];
#pragma unroll
        for (int c = 0; c < 4; ++c) {
            wr[c]  = Wg[0 * 4 + c] + Wg[1 * 4 + c] + Wg[2 * 4 + c] + Wg[3 * 4 + c];
            bgl[c] = bg[c];
        }
        float v[4];
#pragma unroll
        for (int c = 0; c < 4; ++c) {
            v[c] = tanhf(sj[0] * wr[c] + bgl[c]) + tanhf(sj[1] * wr[c] + bgl[c]) +
                   tanhf(sj[2] * wr[c] + bgl[c]) + tanhf(sj[3] * wr[c] + bgl[c]);
#pragma unroll
            for (int o = 32; o >= 1; o >>= 1) v[c] += __shfl_down(v[c], o, 64);
        }
        float g0 = __shfl(v[0], 0, 64), g1 = __shfl(v[1], 0, 64);
        float g2 = __shfl(v[2], 0, 64), g3 = __shfl(v[3], 0, 64);
        if (tid < 4) {
            float r = blin[tid] + (g0 * Wlin[0 * 4 + tid] + g1 * Wlin[1 * 4 + tid] +
                                   g2 * Wlin[2 * 4 + tid] + g3 * Wlin[3 * 4 + tid]) *
                                      (1.0f / 256.0f);
            coeff[g * 4 + tid] = r;
        }
    }
}

// ---------------------------------------------------------------------------
// Chebyshev propagation via per-sample dense MFMA GEMM (unchanged).
// ---------------------------------------------------------------------------
__global__ __launch_bounds__(256, 2)
void cheb_prop(const unsigned short* __restrict__ Pb,
               const unsigned short* __restrict__ Tc,
               const unsigned short* __restrict__ Tp,
               unsigned short* __restrict__ Tn, int first) {
    __shared__ unsigned short A_lds[128 * 40];
    __shared__ unsigned short B_lds[128 * 40];
    const int b = blockIdx.x, mb = blockIdx.y, cb = blockIdx.z;
    const int tid = threadIdx.x, lane = tid & 63, wv = tid >> 6;
    const int wr = wv & 1, wc = wv >> 1, quad = lane >> 4, l15 = lane & 15;
    const unsigned short* Pbase = Pb + ((size_t)b << 16) + (size_t)mb * 128 * 256;

    floatx4 acc[4][4];
#pragma unroll
    for (int rt = 0; rt < 4; ++rt)
#pragma unroll
        for (int ct = 0; ct < 4; ++ct) acc[rt][ct] = (floatx4){0.f, 0.f, 0.f, 0.f};

    for (int kt = 0; kt < 8; ++kt) {
        const int kc = kt * 32;
        __syncthreads();
#pragma unroll
        for (int it = 0; it < 2; ++it) {
            int idx = it * 256 + tid;
            int row = idx >> 2, sub = idx & 3;
            *(uint4*)(A_lds + row * 40 + sub * 8) =
                *(const uint4*)(Pbase + row * 256 + kc + sub * 8);
            *(uint4*)(B_lds + row * 40 + sub * 8) =
                *(const uint4*)(Tc + (size_t)(cb * 128 + row) * 16384 + b * 256 + kc + sub * 8);
        }
        __syncthreads();
        short8 af[4], bfr[4];
#pragma unroll
        for (int rt = 0; rt < 4; ++rt)
            af[rt] = *(const short8*)(A_lds + (wr * 64 + rt * 16 + l15) * 40 + quad * 8);
#pragma unroll
        for (int ct = 0; ct < 4; ++ct)
            bfr[ct] = *(const short8*)(B_lds + (wc * 64 + ct * 16 + l15) * 40 + quad * 8);
#pragma unroll
        for (int rt = 0; rt < 4; ++rt)
#pragma unroll
            for (int ct = 0; ct < 4; ++ct)
                acc[rt][ct] = __builtin_amdgcn_mfma_f32_16x16x32_bf16(af[rt], bfr[ct],
                                                                     acc[rt][ct], 0, 0, 0);
    }
#pragma unroll
    for (int rt = 0; rt < 4; ++rt)
#pragma unroll
        for (int ct = 0; ct < 4; ++ct) {
            int col = cb * 128 + wc * 64 + ct * 16 + l15;
            int m = mb * 128 + wr * 64 + rt * 16 + quad * 4;
            size_t base = (size_t)col * 16384 + b * 256 + m;
            float v[4];
            if (first) {
#pragma unroll
                for (int i = 0; i < 4; ++i) v[i] = acc[rt][ct][i];
            } else {
                uint2 tp = *(const uint2*)(Tp + base);
                v[0] = 2.0f * acc[rt][ct][0] - bf2f((unsigned short)(tp.x & 0xffff));
                v[1] = 2.0f * acc[rt][ct][1] - bf2f((unsigned short)(tp.x >> 16));
                v[2] = 2.0f * acc[rt][ct][2] - bf2f((unsigned short)(tp.y & 0xffff));
                v[3] = 2.0f * acc[rt][ct][3] - bf2f((unsigned short)(tp.y >> 16));
            }
            unsigned int lo = (unsigned int)f2bf(v[0]) | ((unsigned int)f2bf(v[1]) << 16);
            unsigned int hi = (unsigned int)f2bf(v[2]) | ((unsigned int)f2bf(v[3]) << 16);
            *(uint2*)(Tn + base) = make_uint2(lo, hi);
        }
}

// ---------------------------------------------------------------------------
// filt v2: consumes T_k in [col][node] layout DIRECTLY (trn kernels deleted).
// A_lds layout: [node][blk][8] with blk_phys = blk ^ ((node>>3)&7)  (XOR swizzle
// so the transpose-staging scalar-ish writes are ~4-way instead of 32-way).
// ck scaling moved to the W tile (64x64, from fp32 source).
// filtb[(n*B+b)*512 + h*64 + c] = bf16( b_cheb[c] + sum_k (T_k @ (ck*W_cheb[k])) )
// ---------------------------------------------------------------------------
__global__ __launch_bounds__(256, 2)
void filt_kernel(const float* __restrict__ oeh,
                 const unsigned short* __restrict__ T1t, const unsigned short* __restrict__ T2t,
                 const unsigned short* __restrict__ T3t, const float* __restrict__ WchTf,
                 const float* __restrict__ coeff, const float* __restrict__ bch,
                 unsigned short* __restrict__ filtb) {
    __shared__ unsigned short A_lds[256 * 72];  // 36 KB
    __shared__ unsigned short W_lds[64 * 72];   // 9 KB
    const int b = blockIdx.x, h = blockIdx.y;
    const int tid = threadIdx.x, lane = tid & 63, wv = tid >> 6;
    const int quad = lane >> 4, l15 = lane & 15;

    floatx4 acc[4][4];
#pragma unroll
    for (int rt = 0; rt < 4; ++rt)
#pragma unroll
        for (int ct = 0; ct < 4; ++ct) acc[rt][ct] = (floatx4){0.f, 0.f, 0.f, 0.f};

    for (int k = 0; k < 4; ++k) {
        float ck = coeff[(h * Bq + b) * 4 + k];
        __syncthreads();
        if (k == 0) {
            // A = oeh slice (fp32 -> bf16), [node][dh], swizzled blocks
#pragma unroll
            for (int it = 0; it < 8; ++it) {
                int idx = it * 256 + tid;
                int row = idx >> 3, sub = idx & 7;
                const float* sp = oeh + (size_t)(b * 256 + row) * 512 + h * 64 + sub * 8;
                float4 v0 = *(const float4*)sp;
                float4 v1 = *(const float4*)(sp + 4);
                unsigned int p0 = (unsigned int)f2bf(v0.x) | ((unsigned int)f2bf(v0.y) << 16);
                unsigned int p1 = (unsigned int)f2bf(v0.z) | ((unsigned int)f2bf(v0.w) << 16);
                unsigned int p2 = (unsigned int)f2bf(v1.x) | ((unsigned int)f2bf(v1.y) << 16);
                unsigned int p3 = (unsigned int)f2bf(v1.z) | ((unsigned int)f2bf(v1.w) << 16);
                *(uint4*)(A_lds + row * 72 + ((sub ^ ((row >> 3) & 7)) << 3)) =
                    make_uint4(p0, p1, p2, p3);
            }
        } else {
            // A = T_k in [col][node] layout: coalesced read + 2x2 register
            // micro-transpose -> swizzled [node][dh] LDS writes (uint each).
            const unsigned short* Tk = (k == 1) ? T1t : (k == 2) ? T2t : T3t;
            const unsigned short* base = Tk + (size_t)(h * 64) * 16384 + b * 256;
#pragma unroll
            for (int it = 0; it < 4; ++it) {
                int idx = it * 256 + tid;
                int cr2 = idx >> 5;          // 0..31 -> col pair (crA, crA+1)
                int nch = idx & 31;          // node chunk (8 nodes)
                int n0 = nch * 8;
                int crA = cr2 * 2;
                uint4 a  = *(const uint4*)(base + (size_t)crA * 16384 + n0);
                uint4 c4 = *(const uint4*)(base + (size_t)(crA + 1) * 16384 + n0);
                unsigned swz = (unsigned)((((crA >> 3) ^ (nch & 7)) << 3) + (crA & 7));
                unsigned short* dst = A_lds + swz;
                unsigned av[4] = {a.x, a.y, a.z, a.w};
                unsigned cv4[4] = {c4.x, c4.y, c4.z, c4.w};
#pragma unroll
                for (int w2 = 0; w2 < 4; ++w2) {
                    unsigned lo = (av[w2] & 0xffffu) | (cv4[w2] << 16);
                    unsigned hi = (av[w2] >> 16) | (cv4[w2] & 0xffff0000u);
                    *(unsigned*)(dst + (n0 + w2 * 2 + 0) * 72) = lo;
                    *(unsigned*)(dst + (n0 + w2 * 2 + 1) * 72) = hi;
                }
            }
        }
        // W tile, scaled by ck (from fp32 source -> single rounding)
#pragma unroll
        for (int it = 0; it < 2; ++it) {
            int idx = it * 256 + tid;
            int r = idx >> 3, sub = idx & 7;
            const float* wp = WchTf + k * 4096 + r * 64 + sub * 8;
            float4 w0 = *(const float4*)wp;
            float4 w1 = *(const float4*)(wp + 4);
            unsigned int p0 = (unsigned int)f2bf(w0.x * ck) | ((unsigned int)f2bf(w0.y * ck) << 16);
            unsigned int p1 = (unsigned int)f2bf(w0.z * ck) | ((unsigned int)f2bf(w0.w * ck) << 16);
            unsigned int p2 = (unsigned int)f2bf(w1.x * ck) | ((unsigned int)f2bf(w1.y * ck) << 16);
            unsigned int p3 = (unsigned int)f2bf(w1.z * ck) | ((unsigned int)f2bf(w1.w * ck) << 16);
            *(uint4*)(W_lds + r * 72 + sub * 8) = make_uint4(p0, p1, p2, p3);
        }
        __syncthreads();
#pragma unroll
        for (int kk = 0; kk < 2; ++kk) {
            short8 af[4], bfr[4];
#pragma unroll
            for (int rt = 0; rt < 4; ++rt) {
                int node = wv * 64 + rt * 16 + l15;
                int blk = ((kk << 2) + quad) ^ ((node >> 3) & 7);
                af[rt] = *(const short8*)(A_lds + node * 72 + (blk << 3));
            }
#pragma unroll
            for (int ct = 0; ct < 4; ++ct)
                bfr[ct] = *(const short8*)(W_lds + (ct * 16 + l15) * 72 + kk * 32 + quad * 8);
#pragma unroll
            for (int rt = 0; rt < 4; ++rt)
#pragma unroll
                for (int ct = 0; ct < 4; ++ct)
                    acc[rt][ct] = __builtin_amdgcn_mfma_f32_16x16x32_bf16(af[rt], bfr[ct],
                                                                         acc[rt][ct], 0, 0, 0);
        }
    }
#pragma unroll
    for (int rt = 0; rt < 4; ++rt)
#pragma unroll
        for (int ct = 0; ct < 4; ++ct) {
            int coln = ct * 16 + l15;
            float bias = bch[coln];
#pragma unroll
            for (int i = 0; i < 4; ++i) {
                int m = wv * 64 + rt * 16 + quad * 4 + i;  // local node n
                size_t r = (size_t)m * 64 + b;             // n*B + b
                filtb[r * 512 + h * 64 + coln] = f2bf(acc[rt][ct][i] + bias);
            }
        }
}

// ---------------------------------------------------------------------------
// W_cat (1024 x 512 fp32) -> Wt2 bf16 in MFMA-fragment order.
// ---------------------------------------------------------------------------
__global__ void wt2_kernel(const float* __restrict__ W, unsigned short* __restrict__ Wt2) {
    int idx = blockIdx.x * 256 + threadIdx.x;   // 0..65535
    int col = idx & 511;
    int ktq = idx >> 9;                         // 0..127 ; k base = ktq*8
    const float* src = W + (size_t)(ktq * 8) * 512 + col;
    unsigned int pk[4];
#pragma unroll
    for (int q2 = 0; q2 < 4; ++q2) {
        unsigned short a = f2bf(src[(q2 * 2 + 0) * 512]);
        unsigned short b = f2bf(src[(q2 * 2 + 1) * 512]);
        pk[q2] = (unsigned int)a | ((unsigned int)b << 16);
    }
    *(uint4*)(Wt2 + (size_t)idx * 8) = make_uint4(pk[0], pk[1], pk[2], pk[3]);
}

// ---------------------------------------------------------------------------
// MFMA GEMM (M=16384, K=1024, N=512) + fused LayerNorm (unchanged from r1).
// ---------------------------------------------------------------------------
__global__ __launch_bounds__(512, 2)
void gemm_ln_mfma(const float* __restrict__ outp, const unsigned short* __restrict__ filtb,
                  const unsigned short* __restrict__ Wt2, const float* __restrict__ bcat,
                  const float* __restrict__ gamma, const float* __restrict__ beta,
                  float* __restrict__ out) {
    extern __shared__ unsigned char smc[];
    unsigned short* A_lds0 = (unsigned short*)smc;           // 4 KB
    unsigned short* A_lds1 = (unsigned short*)(smc + 4096);  // 4 KB
    float* ep = (float*)smc;                                 // 64 KB epilogue overlay

    const int tid = threadIdx.x;
    const int lane = tid & 63;
    const int wv = tid >> 6;
    const int quad = lane >> 4;
    const int l15 = lane & 15;
    const int r0 = blockIdx.x * 64;

    const int s_row = tid >> 3;
    const int s_sub = tid & 7;
    const int s_q   = s_sub >> 1;
    const int s_e   = (s_sub & 1) * 4;

    const size_t boff = (size_t)(quad * 512 + wv * 64 + l15) * 8;

    floatx4 acc[4][4];
#pragma unroll
    for (int rt = 0; rt < 4; ++rt)
#pragma unroll
        for (int ct = 0; ct < 4; ++ct) acc[rt][ct] = (floatx4){0.f, 0.f, 0.f, 0.f};

    short8 bA[4], bB[4];

    {
#pragma unroll
        for (int ct = 0; ct < 4; ++ct)
            bA[ct] = *(const short8*)(Wt2 + boff + ct * 128);
        float4 av = *(const float4*)(outp + (size_t)(r0 + s_row) * 512 + s_sub * 4);
        uint2 ap;
        ap.x = (unsigned int)f2bf(av.x) | ((unsigned int)f2bf(av.y) << 16);
        ap.y = (unsigned int)f2bf(av.z) | ((unsigned int)f2bf(av.w) << 16);
        *(uint2*)(A_lds0 + (s_q * 64 + s_row) * 8 + s_e) = ap;
        __syncthreads();
    }

#define GSTEP(KT, BC, BN, AC, AN, HASNEXT)                                          \
    do {                                                                            \
        const int kt_ = (KT);                                                       \
        const bool hn_ = (HASNEXT);                                                 \
        const bool isf_ = (kt_ + 1 < 16);                                           \
        float4 av_; uint2 afb_;                                                     \
        if (hn_) {                                                                  \
            _Pragma("unroll")                                                       \
            for (int ct = 0; ct < 4; ++ct)                                          \
                BN[ct] = *(const short8*)(Wt2 + (size_t)(kt_ + 1) * 16384 +         \
                                          boff + ct * 128);                         \
            const int kc_ = (kt_ + 1) * 32;                                         \
            if (isf_)                                                               \
                av_ = *(const float4*)(outp + (size_t)(r0 + s_row) * 512 +          \
                                       kc_ + s_sub * 4);                            \
            else                                                                    \
                afb_ = *(const uint2*)(filtb + (size_t)(r0 + s_row) * 512 +         \
                                       (kc_ - 512) + s_sub * 4);                    \
        }                                                                           \
        short8 af_[4];                                                              \
        _Pragma("unroll")                                                           \
        for (int rt = 0; rt < 4; ++rt)                                              \
            af_[rt] = *(const short8*)(AC + (quad * 64 + rt * 16 + l15) * 8);       \
        _Pragma("unroll")                                                           \
        for (int rt = 0; rt < 4; ++rt)                                              \
            _Pragma("unroll")                                                       \
            for (int ct = 0; ct < 4; ++ct)                                          \
                acc[rt][ct] = __builtin_amdgcn_mfma_f32_16x16x32_bf16(              \
                    af_[rt], BC[ct], acc[rt][ct], 0, 0, 0);                         \
        if (hn_) {                                                                  \
            uint2 ap_;                                                              \
            if (isf_) {                                                             \
                ap_.x = (unsigned int)f2bf(av_.x) | ((unsigned int)f2bf(av_.y) << 16); \
                ap_.y = (unsigned int)f2bf(av_.z) | ((unsigned int)f2bf(av_.w) << 16); \
            } else {                                                                \
                ap_ = afb_;                                                         \
            }                                                                       \
            *(uint2*)(AN + (s_q * 64 + s_row) * 8 + s_e) = ap_;                     \
        }                                                                           \
        __syncthreads();                                                            \
    } while (0)

    for (int kt2 = 0; kt2 < 16; ++kt2) {
        GSTEP(2 * kt2,     bA, bB, A_lds0, A_lds1, true);
        GSTEP(2 * kt2 + 1, bB, bA, A_lds1, A_lds0, kt2 < 15);
    }
#undef GSTEP

    float gg[8], bb[8];
#pragma unroll
    for (int i = 0; i < 8; ++i) { gg[i] = gamma[i * 64 + lane]; bb[i] = beta[i * 64 + lane]; }
    float bc[4];
#pragma unroll
    for (int ct = 0; ct < 4; ++ct) bc[ct] = bcat[wv * 64 + ct * 16 + l15];

    for (int half = 0; half < 2; ++half) {
        __syncthreads();
#pragma unroll
        for (int rt2 = 0; rt2 < 2; ++rt2) {
            const int rt = half * 2 + rt2;
#pragma unroll
            for (int ct = 0; ct < 4; ++ct) {
                const int col = wv * 64 + ct * 16 + l15;
#pragma unroll
                for (int i = 0; i < 4; ++i) {
                    const int row_l = rt2 * 16 + quad * 4 + i;
                    ep[row_l * 512 + col] = acc[rt][ct][i] + bc[ct];
                }
            }
        }
        __syncthreads();
#pragma unroll
        for (int m4 = 0; m4 < 4; ++m4) {
            const int m = wv * 4 + m4;
            float s = 0.0f, ss = 0.0f;
#pragma unroll
            for (int i = 0; i < 8; ++i) {
                float v = ep[m * 512 + i * 64 + lane];
                s += v; ss += v * v;
            }
#pragma unroll
            for (int o = 32; o >= 1; o >>= 1) {
                s += __shfl_down(s, o, 64);
                ss += __shfl_down(ss, o, 64);
            }
            s = __shfl(s, 0, 64);
            ss = __shfl(ss, 0, 64);
            const float mu = s * (1.0f / 512.0f);
            const float var = ss * (1.0f / 512.0f) - mu * mu;
            const float rs = rsqrtf(var + 1e-5f);
            const int r = r0 + half * 32 + m;
#pragma unroll
            for (int i = 0; i < 8; ++i) {
                const int d = i * 64 + lane;
                out[(size_t)r * 512 + d] = (ep[m * 512 + d] - mu) * rs * gg[i] + bb[i];
            }
        }
    }
}

// ---------------------------------------------------------------------------
// Launch
// ---------------------------------------------------------------------------
extern "C" void kernel_launch(void* const* d_in, const int* in_sizes, int n_in,
                              void* d_out, int out_size, void* d_ws, size_t ws_size,
                              hipStream_t stream) {
    const float* output       = (const float*)d_in[0];
    const float* attn         = (const float*)d_in[1];
    const float* oeh          = (const float*)d_in[2];
    const int*   edge_index   = (const int*)d_in[3];
    const float* W_gcn        = (const float*)d_in[6];
    const float* b_gcn        = (const float*)d_in[7];
    const float* W_lin        = (const float*)d_in[8];
    const float* b_lin        = (const float*)d_in[9];
    const float* W_cheb       = (const float*)d_in[10];
    const float* b_cheb       = (const float*)d_in[11];
    const float* W_cat        = (const float*)d_in[12];
    const float* b_cat        = (const float*)d_in[13];
    const float* gamma        = (const float*)d_in[14];
    const float* beta         = (const float*)d_in[15];
    float* out = (float*)d_out;

    const int E = in_sizes[3] / 2;
    const int* srcp = edge_index;
    const int* dstp = edge_index + E;

    uint8_t* ws = (uint8_t*)d_ws;
    size_t cur = 0;
    auto alloc = [&](size_t bytes) -> void* {
        void* p = ws + cur;
        cur += (bytes + 255) & ~(size_t)255;
        return p;
    };
    int*   cnt     = (int*)alloc(TOTALq * sizeof(int));
    float* dinv_n  = (float*)alloc(TOTALq * sizeof(float));
    float* Pf      = (float*)alloc((size_t)64 * 65536 * sizeof(float));     // 16.8 MB
    unsigned short* Pb   = (unsigned short*)alloc((size_t)64 * 65536 * 2);  //  8.4 MB
    float* coeff   = (float*)alloc(512 * 4 * sizeof(float));
    unsigned short* X0_t = (unsigned short*)alloc((size_t)512 * 16384 * 2); // 16.8 MB
    unsigned short* T1_t = (unsigned short*)alloc((size_t)512 * 16384 * 2);
    unsigned short* T2_t = (unsigned short*)alloc((size_t)512 * 16384 * 2);
    unsigned short* T3_t = (unsigned short*)alloc((size_t)512 * 16384 * 2);
    float* WchTf   = (float*)alloc(4 * 64 * 64 * sizeof(float));
    unsigned short* Wt2  = (unsigned short*)alloc((size_t)Dq * 1024 * 2);
    unsigned short* filtb = (unsigned short*)alloc((size_t)TOTALq * Dq * 2);
    (void)ws_size; (void)n_in; (void)out_size;

    hipMemsetAsync(cnt, 0, TOTALq * sizeof(int), stream);
    count_deg_kernel<<<(E + 255) / 256, 256, 0, stream>>>(dstp, cnt, E);
    dinv_kernel<<<TOTALq / 256, 256, 0, stream>>>(cnt, dinv_n);
    hipMemsetAsync(Pf, 0, (size_t)64 * 65536 * sizeof(float), stream);
    pscatter_kernel<<<(E + 255) / 256, 256, 0, stream>>>(srcp, dstp, dinv_n, Pf, E);
    pconv_kernel<<<4096, 256, 0, stream>>>(Pf, Pb);

    x0t_kernel<<<dim3(256, 8), 256, 0, stream>>>(oeh, X0_t);
    coeff_kernel<<<Hq * Bq, 512, 0, stream>>>(attn, W_gcn, b_gcn, W_lin, b_lin, coeff);
    wt2_kernel<<<256, 256, 0, stream>>>(W_cat, Wt2);
    wchebt_kernel<<<64, 256, 0, stream>>>(W_cheb, WchTf);

    dim3 pg(64, 2, 4);
    cheb_prop<<<pg, 256, 0, stream>>>(Pb, X0_t, nullptr, T1_t, 1);
    cheb_prop<<<pg, 256, 0, stream>>>(Pb, T1_t, X0_t, T2_t, 0);
    cheb_prop<<<pg, 256, 0, stream>>>(Pb, T2_t, T1_t, T3_t, 0);

    filt_kernel<<<dim3(64, 8), 256, 0, stream>>>(oeh, T1_t, T2_t, T3_t, WchTf, coeff,
                                                 b_cheb, filtb);

    gemm_ln_mfma<<<TOTALq / 64, 512, 65536, stream>>>(output, filtb, Wt2, b_cat,
                                                      gamma, beta, out);
}

// Round 4
// 414.394 us; speedup vs baseline: 1.2029x; 1.0546x over previous
//
#include <hip/hip_runtime.h>
#include <stdint.h>

// Problem constants (fixed by the reference):
#define Bq      64
#define Nq      256
#define Hq      8
#define DHq     64
#define TOTALq  16384    // B*N
#define NTq     131072   // H*TOTAL
#define Dq      512      // H*DH

typedef __attribute__((ext_vector_type(8))) short short8;
typedef __attribute__((ext_vector_type(4))) float floatx4;

__device__ __forceinline__ unsigned short f2bf(float f) {
    union { float f; unsigned int u; } c; c.f = f;
    unsigned int u = c.u;
    return (unsigned short)((u + 0x7fffu + ((u >> 16) & 1u)) >> 16);
}
__device__ __forceinline__ float bf2f(unsigned short u) {
    union { unsigned int u; float f; } c; c.u = ((unsigned int)u) << 16;
    return c.f;
}

// ---------------------------------------------------------------------------
// Graph structure: degree -> dinv; dense per-sample P (64 x 256 x 256)
// ---------------------------------------------------------------------------

__global__ void count_deg_kernel(const int* __restrict__ dstp, int* __restrict__ cnt, int E) {
    int e = blockIdx.x * 256 + threadIdx.x;
    if (e < E) atomicAdd(&cnt[dstp[e]], 1);
}

__global__ void dinv_kernel(const int* __restrict__ cnt, float* __restrict__ dinv_n) {
    int v = blockIdx.x * 256 + threadIdx.x;
    if (v < TOTALq) {
        int c = cnt[v];
        dinv_n[v] = (c > 0) ? rsqrtf((float)c) : 0.0f;
    }
}

__global__ void pscatter_kernel(const int* __restrict__ srcp, const int* __restrict__ dstp,
                                const float* __restrict__ dinv_n, float* __restrict__ Pf, int E) {
    int e = blockIdx.x * 256 + threadIdx.x;
    if (e >= E) return;
    int s = srcp[e], d = dstp[e];
    int g = d >> 8;  // sample index
    atomicAdd(&Pf[((size_t)g << 16) + ((size_t)(d & 255) << 8) + (s & 255)],
              -(dinv_n[s] * dinv_n[d]));
}

__global__ void pconv_kernel(const float* __restrict__ Pf, unsigned short* __restrict__ Pb) {
    int i = (blockIdx.x * 256 + threadIdx.x) * 4;
    float4 v = *(const float4*)(Pf + i);
    unsigned int lo = (unsigned int)f2bf(v.x) | ((unsigned int)f2bf(v.y) << 16);
    unsigned int hi = (unsigned int)f2bf(v.z) | ((unsigned int)f2bf(v.w) << 16);
    *(uint2*)(Pb + i) = make_uint2(lo, hi);
}

// W_cheb (4 x 64 x 64, [k][j][n]) -> WchTf fp32 [k][n][j]  (scaled+bf16'd in cheb_fused)
__global__ void wchebt_kernel(const float* __restrict__ W, float* __restrict__ WT) {
    int idx = blockIdx.x * 256 + threadIdx.x;  // 16384 total
    int k = idx >> 12, rem = idx & 4095;
    int n = rem >> 6, j = rem & 63;
    WT[idx] = W[(k << 12) + (j << 6) + n];
}

// ---------------------------------------------------------------------------
// Coefficient kernel: one block per graph g = h*B + b; 512 thr, float4 cols.
// ---------------------------------------------------------------------------
__global__ __launch_bounds__(512)
void coeff_kernel(const float* __restrict__ attn,
                  const float* __restrict__ Wg, const float* __restrict__ bg,
                  const float* __restrict__ Wlin, const float* __restrict__ blin,
                  float* __restrict__ coeff) {
    __shared__ floatx4 part[8][64];   // 8 KB
    __shared__ floatx4 dinv4[64];     // 1 KB (256 dinv values)
    const int g = blockIdx.x;
    const int h = g >> 6;
    const int b = g & 63;
    const float* A = attn + ((size_t)(b * Hq + h)) * (Nq * Nq);
    const int tid = threadIdx.x;
    const int rg = tid >> 6;          // 8 row groups of 32 rows
    const int cv = tid & 63;          // float4 column group
    const float* Ap = A + cv * 4;

    floatx4 s1 = (floatx4){0.f, 0.f, 0.f, 0.f};
#pragma unroll 8
    for (int r = 0; r < 32; ++r)
        s1 += *(const floatx4*)(Ap + (size_t)(rg * 32 + r) * 256);
    part[rg][cv] = s1;
    __syncthreads();

    if (tid < 64) {
        floatx4 cs = part[0][tid];
#pragma unroll
        for (int i = 1; i < 8; ++i) cs += part[i][tid];
        floatx4 dv;
#pragma unroll
        for (int i = 0; i < 4; ++i) dv[i] = rsqrtf(cs[i] + 1.0f);
        dinv4[tid] = dv;
    }
    __syncthreads();

    const float* dsc = (const float*)dinv4;
    floatx4 s2 = (floatx4){0.f, 0.f, 0.f, 0.f};
#pragma unroll 8
    for (int r = 0; r < 32; ++r) {
        int rr = rg * 32 + r;
        s2 += dsc[rr] * (*(const floatx4*)(Ap + (size_t)rr * 256));
    }
    part[rg][cv] = s2;
    __syncthreads();

    if (tid < 64) {
        floatx4 ws = part[0][tid];
#pragma unroll
        for (int i = 1; i < 8; ++i) ws += part[i][tid];
        floatx4 dv = dinv4[tid];
        floatx4 sj = (ws + dv) * dv;

        float wr[4], bgl[4];
#pragma unroll
        for (int c = 0; c < 4; ++c) {
            wr[c]  = Wg[0 * 4 + c] + Wg[1 * 4 + c] + Wg[2 * 4 + c] + Wg[3 * 4 + c];
            bgl[c] = bg[c];
        }
        float v[4];
#pragma unroll
        for (int c = 0; c < 4; ++c) {
            v[c] = tanhf(sj[0] * wr[c] + bgl[c]) + tanhf(sj[1] * wr[c] + bgl[c]) +
                   tanhf(sj[2] * wr[c] + bgl[c]) + tanhf(sj[3] * wr[c] + bgl[c]);
#pragma unroll
            for (int o = 32; o >= 1; o >>= 1) v[c] += __shfl_down(v[c], o, 64);
        }
        float g0 = __shfl(v[0], 0, 64), g1 = __shfl(v[1], 0, 64);
        float g2 = __shfl(v[2], 0, 64), g3 = __shfl(v[3], 0, 64);
        if (tid < 4) {
            float r = blin[tid] + (g0 * Wlin[0 * 4 + tid] + g1 * Wlin[1 * 4 + tid] +
                                   g2 * Wlin[2 * 4 + tid] + g3 * Wlin[3 * 4 + tid]) *
                                      (1.0f / 256.0f);
            coeff[g * 4 + tid] = r;
        }
    }
}

// ---------------------------------------------------------------------------
// FUSED Chebyshev recursion + filter. One block per (sample b, head h).
// T_k (256 nodes x 64 feats) lives in LDS in TWO swizzled layouts:
//   cm[feat c][node s]: B-operand for prop  (addr = c*256 + ((s>>3)^(c&31))*8 + (s&7))
//   rm[node m][feat c]: A-operand for filt  (addr = m*64  + ((c>>3)^(m&7))*8  + (c&7))
// P_b (256x256 bf16) streamed as A-fragments straight from global (L2-hot).
// T_{k-1}/T_k kept per-thread in packed regs for the "- T_{k-1}" term.
// accf accumulates sum_k T_k @ (ck*W_k); epilogue adds b_cheb, writes filtb bf16.
// 512 thr = 8 waves (4 row groups x 2 col groups); 73 KB dynamic LDS.
// ---------------------------------------------------------------------------
__global__ __launch_bounds__(512, 2)
void cheb_fused(const unsigned short* __restrict__ Pb, const float* __restrict__ oeh,
                const float* __restrict__ WchTf, const float* __restrict__ coeff,
                const float* __restrict__ bch, unsigned short* __restrict__ filtb) {
    extern __shared__ unsigned char sm[];
    unsigned short* cm = (unsigned short*)sm;            // [64][256] swizzled, 32 KB
    unsigned short* rm = (unsigned short*)(sm + 32768);  // [256][64] swizzled, 32 KB
    unsigned short* Wl = (unsigned short*)(sm + 65536);  // [64][72], 9 KB

    const int g = blockIdx.x;
    const int b = (g & 7) * 8 + ((g >> 3) & 7);  // XCD-chunked: same b -> same XCD
    const int h = g >> 6;
    const int tid = threadIdx.x;
    const int lane = tid & 63, wv = tid >> 6;
    const int wr = wv >> 1, wc = wv & 1;
    const int quad = lane >> 4, l15 = lane & 15;

    const unsigned short* Pbase = Pb + ((size_t)b << 16);
    const float* cf = coeff + (h * 64 + b) * 4;

    // ---- stage X0 (cm + rm) and W0 ----
    {
        const int sn = tid >> 1;
        const int sh = (tid & 1) * 32;
        const float* sp = oeh + (size_t)(b * 256 + sn) * 512 + h * 64 + sh;
        unsigned int pk[16];
#pragma unroll
        for (int j = 0; j < 8; ++j) {
            float4 v = *(const float4*)(sp + j * 4);
            pk[2 * j]     = (unsigned)f2bf(v.x) | ((unsigned)f2bf(v.y) << 16);
            pk[2 * j + 1] = (unsigned)f2bf(v.z) | ((unsigned)f2bf(v.w) << 16);
        }
#pragma unroll
        for (int jj = 0; jj < 4; ++jj)
            *(uint4*)(rm + sn * 64 + ((((sh >> 3) + jj) ^ (sn & 7)) << 3)) =
                make_uint4(pk[4 * jj], pk[4 * jj + 1], pk[4 * jj + 2], pk[4 * jj + 3]);
#pragma unroll
        for (int e = 0; e < 32; ++e) {
            int c = sh + e;
            unsigned short v =
                (unsigned short)((e & 1) ? (pk[e >> 1] >> 16) : (pk[e >> 1] & 0xffffu));
            cm[c * 256 + (((sn >> 3) ^ (c & 31)) << 3) + (sn & 7)] = v;
        }
        float ck = cf[0];
        int r = tid >> 3, su = tid & 7;
        const float* wp = WchTf + r * 64 + su * 8;
        float4 w0 = *(const float4*)wp, w1 = *(const float4*)(wp + 4);
        *(uint4*)(Wl + r * 72 + su * 8) = make_uint4(
            (unsigned)f2bf(w0.x * ck) | ((unsigned)f2bf(w0.y * ck) << 16),
            (unsigned)f2bf(w0.z * ck) | ((unsigned)f2bf(w0.w * ck) << 16),
            (unsigned)f2bf(w1.x * ck) | ((unsigned)f2bf(w1.y * ck) << 16),
            (unsigned)f2bf(w1.z * ck) | ((unsigned)f2bf(w1.w * ck) << 16));
    }
    __syncthreads();

    // owned T0 elements into regs (packed bf16 pairs over consecutive rows)
    unsigned int curp[4][2][2], prvp[4][2][2];
#pragma unroll
    for (int rt = 0; rt < 4; ++rt)
#pragma unroll
        for (int ct = 0; ct < 2; ++ct)
#pragma unroll
            for (int p = 0; p < 2; ++p) {
                int m = wr * 64 + rt * 16 + quad * 4 + 2 * p;
                int c = wc * 32 + ct * 16 + l15;
                curp[rt][ct][p] = *(const unsigned int*)(cm + c * 256 +
                                                         (((m >> 3) ^ (c & 31)) << 3) + (m & 7));
                prvp[rt][ct][p] = 0u;
            }

    floatx4 accf[4][2];
#pragma unroll
    for (int rt = 0; rt < 4; ++rt)
#pragma unroll
        for (int ct = 0; ct < 2; ++ct) accf[rt][ct] = (floatx4){0.f, 0.f, 0.f, 0.f};

#pragma unroll
    for (int k = 0; k < 4; ++k) {
        // ---- filt_k: accf += T_k(rm) @ (ck*W_k)(Wl) ----
#pragma unroll
        for (int kk = 0; kk < 2; ++kk) {
            short8 af[4], bfw[2];
#pragma unroll
            for (int rt = 0; rt < 4; ++rt) {
                int row = wr * 64 + rt * 16 + l15;
                af[rt] = *(const short8*)(rm + row * 64 + (((kk * 4 + quad) ^ (row & 7)) << 3));
            }
#pragma unroll
            for (int ct = 0; ct < 2; ++ct) {
                int oc = wc * 32 + ct * 16 + l15;
                bfw[ct] = *(const short8*)(Wl + oc * 72 + kk * 32 + quad * 8);
            }
#pragma unroll
            for (int rt = 0; rt < 4; ++rt)
#pragma unroll
                for (int ct = 0; ct < 2; ++ct)
                    accf[rt][ct] = __builtin_amdgcn_mfma_f32_16x16x32_bf16(
                        af[rt], bfw[ct], accf[rt][ct], 0, 0, 0);
        }
        if (k < 3) {
            // ---- prop: accp = P @ T_k  (A from global, B from cm) ----
            floatx4 accp[4][2];
#pragma unroll
            for (int rt = 0; rt < 4; ++rt)
#pragma unroll
                for (int ct = 0; ct < 2; ++ct) accp[rt][ct] = (floatx4){0.f, 0.f, 0.f, 0.f};
#pragma unroll
            for (int kt = 0; kt < 8; ++kt) {
                short8 ap[4], bp[2];
#pragma unroll
                for (int rt = 0; rt < 4; ++rt) {
                    int row = wr * 64 + rt * 16 + l15;
                    ap[rt] = *(const short8*)(Pbase + row * 256 + kt * 32 + quad * 8);
                }
#pragma unroll
                for (int ct = 0; ct < 2; ++ct) {
                    int c = wc * 32 + ct * 16 + l15;
                    bp[ct] = *(const short8*)(cm + c * 256 + (((kt * 4 + quad) ^ (c & 31)) << 3));
                }
#pragma unroll
                for (int rt = 0; rt < 4; ++rt)
#pragma unroll
                    for (int ct = 0; ct < 2; ++ct)
                        accp[rt][ct] = __builtin_amdgcn_mfma_f32_16x16x32_bf16(
                            ap[rt], bp[ct], accp[rt][ct], 0, 0, 0);
            }
            __syncthreads();  // all reads of cm/rm/Wl done
            // ---- write T_{k+1}; rotate regs; stage W_{k+1} ----
#pragma unroll
            for (int rt = 0; rt < 4; ++rt)
#pragma unroll
                for (int ct = 0; ct < 2; ++ct)
#pragma unroll
                    for (int p = 0; p < 2; ++p) {
                        float a0 = accp[rt][ct][2 * p], a1 = accp[rt][ct][2 * p + 1];
                        if (k > 0) {
                            unsigned pv = prvp[rt][ct][p];
                            a0 = 2.0f * a0 - bf2f((unsigned short)(pv & 0xffffu));
                            a1 = 2.0f * a1 - bf2f((unsigned short)(pv >> 16));
                        }
                        unsigned nv = (unsigned)f2bf(a0) | ((unsigned)f2bf(a1) << 16);
                        prvp[rt][ct][p] = curp[rt][ct][p];
                        curp[rt][ct][p] = nv;
                        int m = wr * 64 + rt * 16 + quad * 4 + 2 * p;
                        int c = wc * 32 + ct * 16 + l15;
                        if (k < 2)  // T3 never used as prop B-operand
                            *(unsigned int*)(cm + c * 256 + (((m >> 3) ^ (c & 31)) << 3) +
                                             (m & 7)) = nv;
                        rm[m * 64 + (((c >> 3) ^ (m & 7)) << 3) + (c & 7)] =
                            (unsigned short)(nv & 0xffffu);
                        rm[(m + 1) * 64 + (((c >> 3) ^ ((m + 1) & 7)) << 3) + (c & 7)] =
                            (unsigned short)(nv >> 16);
                    }
            {
                float ck = cf[k + 1];
                int r = tid >> 3, su = tid & 7;
                const float* wp = WchTf + (k + 1) * 4096 + r * 64 + su * 8;
                float4 w0 = *(const float4*)wp, w1 = *(const float4*)(wp + 4);
                *(uint4*)(Wl + r * 72 + su * 8) = make_uint4(
                    (unsigned)f2bf(w0.x * ck) | ((unsigned)f2bf(w0.y * ck) << 16),
                    (unsigned)f2bf(w0.z * ck) | ((unsigned)f2bf(w0.w * ck) << 16),
                    (unsigned)f2bf(w1.x * ck) | ((unsigned)f2bf(w1.y * ck) << 16),
                    (unsigned)f2bf(w1.z * ck) | ((unsigned)f2bf(w1.w * ck) << 16));
            }
            __syncthreads();
        }
    }

    // ---- epilogue: filtb[(n*B+b)*512 + h*64 + c] = bf16(accf + b_cheb) ----
    float bias[2];
#pragma unroll
    for (int ct = 0; ct < 2; ++ct) bias[ct] = bch[wc * 32 + ct * 16 + l15];
#pragma unroll
    for (int rt = 0; rt < 4; ++rt)
#pragma unroll
        for (int ct = 0; ct < 2; ++ct) {
            int c = wc * 32 + ct * 16 + l15;
#pragma unroll
            for (int i = 0; i < 4; ++i) {
                int m = wr * 64 + rt * 16 + quad * 4 + i;
                filtb[((size_t)m * 64 + b) * 512 + h * 64 + c] =
                    f2bf(accf[rt][ct][i] + bias[ct]);
            }
        }
}

// ---------------------------------------------------------------------------
// W_cat (1024 x 512 fp32) -> Wt2 bf16 in MFMA-fragment order.
// ---------------------------------------------------------------------------
__global__ void wt2_kernel(const float* __restrict__ W, unsigned short* __restrict__ Wt2) {
    int idx = blockIdx.x * 256 + threadIdx.x;   // 0..65535
    int col = idx & 511;
    int ktq = idx >> 9;                         // 0..127 ; k base = ktq*8
    const float* src = W + (size_t)(ktq * 8) * 512 + col;
    unsigned int pk[4];
#pragma unroll
    for (int q2 = 0; q2 < 4; ++q2) {
        unsigned short a = f2bf(src[(q2 * 2 + 0) * 512]);
        unsigned short b = f2bf(src[(q2 * 2 + 1) * 512]);
        pk[q2] = (unsigned int)a | ((unsigned int)b << 16);
    }
    *(uint4*)(Wt2 + (size_t)idx * 8) = make_uint4(pk[0], pk[1], pk[2], pk[3]);
}

// ---------------------------------------------------------------------------
// MFMA GEMM (M=16384, K=1024, N=512) + fused LayerNorm (unchanged).
// ---------------------------------------------------------------------------
__global__ __launch_bounds__(512, 2)
void gemm_ln_mfma(const float* __restrict__ outp, const unsigned short* __restrict__ filtb,
                  const unsigned short* __restrict__ Wt2, const float* __restrict__ bcat,
                  const float* __restrict__ gamma, const float* __restrict__ beta,
                  float* __restrict__ out) {
    extern __shared__ unsigned char smc[];
    unsigned short* A_lds0 = (unsigned short*)smc;           // 4 KB
    unsigned short* A_lds1 = (unsigned short*)(smc + 4096);  // 4 KB
    float* ep = (float*)smc;                                 // 64 KB epilogue overlay

    const int tid = threadIdx.x;
    const int lane = tid & 63;
    const int wv = tid >> 6;
    const int quad = lane >> 4;
    const int l15 = lane & 15;
    const int r0 = blockIdx.x * 64;

    const int s_row = tid >> 3;
    const int s_sub = tid & 7;
    const int s_q   = s_sub >> 1;
    const int s_e   = (s_sub & 1) * 4;

    const size_t boff = (size_t)(quad * 512 + wv * 64 + l15) * 8;

    floatx4 acc[4][4];
#pragma unroll
    for (int rt = 0; rt < 4; ++rt)
#pragma unroll
        for (int ct = 0; ct < 4; ++ct) acc[rt][ct] = (floatx4){0.f, 0.f, 0.f, 0.f};

    short8 bA[4], bB[4];

    {
#pragma unroll
        for (int ct = 0; ct < 4; ++ct)
            bA[ct] = *(const short8*)(Wt2 + boff + ct * 128);
        float4 av = *(const float4*)(outp + (size_t)(r0 + s_row) * 512 + s_sub * 4);
        uint2 ap;
        ap.x = (unsigned int)f2bf(av.x) | ((unsigned int)f2bf(av.y) << 16);
        ap.y = (unsigned int)f2bf(av.z) | ((unsigned int)f2bf(av.w) << 16);
        *(uint2*)(A_lds0 + (s_q * 64 + s_row) * 8 + s_e) = ap;
        __syncthreads();
    }

#define GSTEP(KT, BC, BN, AC, AN, HASNEXT)                                          \
    do {                                                                            \
        const int kt_ = (KT);                                                       \
        const bool hn_ = (HASNEXT);                                                 \
        const bool isf_ = (kt_ + 1 < 16);                                           \
        float4 av_; uint2 afb_;                                                     \
        if (hn_) {                                                                  \
            _Pragma("unroll")                                                       \
            for (int ct = 0; ct < 4; ++ct)                                          \
                BN[ct] = *(const short8*)(Wt2 + (size_t)(kt_ + 1) * 16384 +         \
                                          boff + ct * 128);                         \
            const int kc_ = (kt_ + 1) * 32;                                         \
            if (isf_)                                                               \
                av_ = *(const float4*)(outp + (size_t)(r0 + s_row) * 512 +          \
                                       kc_ + s_sub * 4);                            \
            else                                                                    \
                afb_ = *(const uint2*)(filtb + (size_t)(r0 + s_row) * 512 +         \
                                       (kc_ - 512) + s_sub * 4);                    \
        }                                                                           \
        short8 af_[4];                                                              \
        _Pragma("unroll")                                                           \
        for (int rt = 0; rt < 4; ++rt)                                              \
            af_[rt] = *(const short8*)(AC + (quad * 64 + rt * 16 + l15) * 8);       \
        _Pragma("unroll")                                                           \
        for (int rt = 0; rt < 4; ++rt)                                              \
            _Pragma("unroll")                                                       \
            for (int ct = 0; ct < 4; ++ct)                                          \
                acc[rt][ct] = __builtin_amdgcn_mfma_f32_16x16x32_bf16(              \
                    af_[rt], BC[ct], acc[rt][ct], 0, 0, 0);                         \
        if (hn_) {                                                                  \
            uint2 ap_;                                                              \
            if (isf_) {                                                             \
                ap_.x = (unsigned int)f2bf(av_.x) | ((unsigned int)f2bf(av_.y) << 16); \
                ap_.y = (unsigned int)f2bf(av_.z) | ((unsigned int)f2bf(av_.w) << 16); \
            } else {                                                                \
                ap_ = afb_;                                                         \
            }                                                                       \
            *(uint2*)(AN + (s_q * 64 + s_row) * 8 + s_e) = ap_;                     \
        }                                                                           \
        __syncthreads();                                                            \
    } while (0)

    for (int kt2 = 0; kt2 < 16; ++kt2) {
        GSTEP(2 * kt2,     bA, bB, A_lds0, A_lds1, true);
        GSTEP(2 * kt2 + 1, bB, bA, A_lds1, A_lds0, kt2 < 15);
    }
#undef GSTEP

    float gg[8], bb[8];
#pragma unroll
    for (int i = 0; i < 8; ++i) { gg[i] = gamma[i * 64 + lane]; bb[i] = beta[i * 64 + lane]; }
    float bc[4];
#pragma unroll
    for (int ct = 0; ct < 4; ++ct) bc[ct] = bcat[wv * 64 + ct * 16 + l15];

    for (int half = 0; half < 2; ++half) {
        __syncthreads();
#pragma unroll
        for (int rt2 = 0; rt2 < 2; ++rt2) {
            const int rt = half * 2 + rt2;
#pragma unroll
            for (int ct = 0; ct < 4; ++ct) {
                const int col = wv * 64 + ct * 16 + l15;
#pragma unroll
                for (int i = 0; i < 4; ++i) {
                    const int row_l = rt2 * 16 + quad * 4 + i;
                    ep[row_l * 512 + col] = acc[rt][ct][i] + bc[ct];
                }
            }
        }
        __syncthreads();
#pragma unroll
        for (int m4 = 0; m4 < 4; ++m4) {
            const int m = wv * 4 + m4;
            float s = 0.0f, ss = 0.0f;
#pragma unroll
            for (int i = 0; i < 8; ++i) {
                float v = ep[m * 512 + i * 64 + lane];
                s += v; ss += v * v;
            }
#pragma unroll
            for (int o = 32; o >= 1; o >>= 1) {
                s += __shfl_down(s, o, 64);
                ss += __shfl_down(ss, o, 64);
            }
            s = __shfl(s, 0, 64);
            ss = __shfl(ss, 0, 64);
            const float mu = s * (1.0f / 512.0f);
            const float var = ss * (1.0f / 512.0f) - mu * mu;
            const float rs = rsqrtf(var + 1e-5f);
            const int r = r0 + half * 32 + m;
#pragma unroll
            for (int i = 0; i < 8; ++i) {
                const int d = i * 64 + lane;
                out[(size_t)r * 512 + d] = (ep[m * 512 + d] - mu) * rs * gg[i] + bb[i];
            }
        }
    }
}

// ---------------------------------------------------------------------------
// Launch
// ---------------------------------------------------------------------------
extern "C" void kernel_launch(void* const* d_in, const int* in_sizes, int n_in,
                              void* d_out, int out_size, void* d_ws, size_t ws_size,
                              hipStream_t stream) {
    const float* output       = (const float*)d_in[0];
    const float* attn         = (const float*)d_in[1];
    const float* oeh          = (const float*)d_in[2];
    const int*   edge_index   = (const int*)d_in[3];
    const float* W_gcn        = (const float*)d_in[6];
    const float* b_gcn        = (const float*)d_in[7];
    const float* W_lin        = (const float*)d_in[8];
    const float* b_lin        = (const float*)d_in[9];
    const float* W_cheb       = (const float*)d_in[10];
    const float* b_cheb       = (const float*)d_in[11];
    const float* W_cat        = (const float*)d_in[12];
    const float* b_cat        = (const float*)d_in[13];
    const float* gamma        = (const float*)d_in[14];
    const float* beta         = (const float*)d_in[15];
    float* out = (float*)d_out;

    const int E = in_sizes[3] / 2;
    const int* srcp = edge_index;
    const int* dstp = edge_index + E;

    uint8_t* ws = (uint8_t*)d_ws;
    size_t cur = 0;
    auto alloc = [&](size_t bytes) -> void* {
        void* p = ws + cur;
        cur += (bytes + 255) & ~(size_t)255;
        return p;
    };
    int*   cnt     = (int*)alloc(TOTALq * sizeof(int));
    float* dinv_n  = (float*)alloc(TOTALq * sizeof(float));
    float* Pf      = (float*)alloc((size_t)64 * 65536 * sizeof(float));     // 16.8 MB
    unsigned short* Pb   = (unsigned short*)alloc((size_t)64 * 65536 * 2);  //  8.4 MB
    float* coeff   = (float*)alloc(512 * 4 * sizeof(float));
    float* WchTf   = (float*)alloc(4 * 64 * 64 * sizeof(float));
    unsigned short* Wt2  = (unsigned short*)alloc((size_t)Dq * 1024 * 2);
    unsigned short* filtb = (unsigned short*)alloc((size_t)TOTALq * Dq * 2);
    (void)ws_size; (void)n_in; (void)out_size;

    hipMemsetAsync(cnt, 0, TOTALq * sizeof(int), stream);
    count_deg_kernel<<<(E + 255) / 256, 256, 0, stream>>>(dstp, cnt, E);
    dinv_kernel<<<TOTALq / 256, 256, 0, stream>>>(cnt, dinv_n);
    hipMemsetAsync(Pf, 0, (size_t)64 * 65536 * sizeof(float), stream);
    pscatter_kernel<<<(E + 255) / 256, 256, 0, stream>>>(srcp, dstp, dinv_n, Pf, E);
    pconv_kernel<<<4096, 256, 0, stream>>>(Pf, Pb);

    coeff_kernel<<<Hq * Bq, 512, 0, stream>>>(attn, W_gcn, b_gcn, W_lin, b_lin, coeff);
    wt2_kernel<<<256, 256, 0, stream>>>(W_cat, Wt2);
    wchebt_kernel<<<64, 256, 0, stream>>>(W_cheb, WchTf);

    cheb_fused<<<512, 512, 74752, stream>>>(Pb, oeh, WchTf, coeff, b_cheb, filtb);

    gemm_ln_mfma<<<TOTALq / 64, 512, 65536, stream>>>(output, filtb, Wt2, b_cat,
                                                      gamma, beta, out);
}

// Round 5
// 402.916 us; speedup vs baseline: 1.2371x; 1.0285x over previous
//
#include <hip/hip_runtime.h>
#include <stdint.h>

// Problem constants (fixed by the reference):
#define Bq      64
#define Nq      256
#define Hq      8
#define DHq     64
#define TOTALq  16384    // B*N
#define NTq     131072   // H*TOTAL
#define Dq      512      // H*DH

typedef __attribute__((ext_vector_type(8))) short short8;
typedef __attribute__((ext_vector_type(4))) float floatx4;

__device__ __forceinline__ unsigned short f2bf(float f) {
    union { float f; unsigned int u; } c; c.f = f;
    unsigned int u = c.u;
    return (unsigned short)((u + 0x7fffu + ((u >> 16) & 1u)) >> 16);
}
__device__ __forceinline__ float bf2f(unsigned short u) {
    union { unsigned int u; float f; } c; c.u = ((unsigned int)u) << 16;
    return c.f;
}

// ---------------------------------------------------------------------------
// Graph structure: degree -> dense per-sample P (64 x 256 x 256)
// ---------------------------------------------------------------------------

__global__ void count_deg_kernel(const int* __restrict__ dstp, int* __restrict__ cnt, int E) {
    int e = blockIdx.x * 256 + threadIdx.x;
    if (e < E) atomicAdd(&cnt[dstp[e]], 1);
}

// dinv folded in: dinv_v = cnt>0 ? rsqrtf(cnt) : 0 — bit-identical to the old
// two-kernel path since the product uses the same rsqrtf outputs.
__global__ void pscatter_kernel(const int* __restrict__ srcp, const int* __restrict__ dstp,
                                const int* __restrict__ cnt, float* __restrict__ Pf, int E) {
    int e = blockIdx.x * 256 + threadIdx.x;
    if (e >= E) return;
    int s = srcp[e], d = dstp[e];
    int cs = cnt[s], cd = cnt[d];
    float dvs = (cs > 0) ? rsqrtf((float)cs) : 0.0f;
    float dvd = (cd > 0) ? rsqrtf((float)cd) : 0.0f;
    int g = d >> 8;  // sample index
    atomicAdd(&Pf[((size_t)g << 16) + ((size_t)(d & 255) << 8) + (s & 255)],
              -(dvs * dvd));
}

__global__ void pconv_kernel(const float* __restrict__ Pf, unsigned short* __restrict__ Pb) {
    int i = (blockIdx.x * 256 + threadIdx.x) * 4;
    float4 v = *(const float4*)(Pf + i);
    unsigned int lo = (unsigned int)f2bf(v.x) | ((unsigned int)f2bf(v.y) << 16);
    unsigned int hi = (unsigned int)f2bf(v.z) | ((unsigned int)f2bf(v.w) << 16);
    *(uint2*)(Pb + i) = make_uint2(lo, hi);
}

// ---------------------------------------------------------------------------
// Merged prep: blocks 0..255 -> Wt2 (W_cat fragment reorder);
//              blocks 256..319 -> WchTf (W_cheb [k][j][n] -> [k][n][j] fp32)
// ---------------------------------------------------------------------------
__global__ void prep_kernel(const float* __restrict__ Wcat, unsigned short* __restrict__ Wt2,
                            const float* __restrict__ Wch, float* __restrict__ WchTf) {
    int bid = blockIdx.x;
    if (bid < 256) {
        int idx = bid * 256 + threadIdx.x;   // 0..65535
        int col = idx & 511;
        int ktq = idx >> 9;                  // 0..127 ; k base = ktq*8
        const float* src = Wcat + (size_t)(ktq * 8) * 512 + col;
        unsigned int pk[4];
#pragma unroll
        for (int q2 = 0; q2 < 4; ++q2) {
            unsigned short a = f2bf(src[(q2 * 2 + 0) * 512]);
            unsigned short b = f2bf(src[(q2 * 2 + 1) * 512]);
            pk[q2] = (unsigned int)a | ((unsigned int)b << 16);
        }
        *(uint4*)(Wt2 + (size_t)idx * 8) = make_uint4(pk[0], pk[1], pk[2], pk[3]);
    } else {
        int idx = (bid - 256) * 256 + threadIdx.x;  // 16384 total
        int k = idx >> 12, rem = idx & 4095;
        int n = rem >> 6, j = rem & 63;
        WchTf[idx] = Wch[(k << 12) + (j << 6) + n];
    }
}

// ---------------------------------------------------------------------------
// Coefficient kernel: one block per graph g = h*B + b; 512 thr, float4 cols.
// ---------------------------------------------------------------------------
__global__ __launch_bounds__(512)
void coeff_kernel(const float* __restrict__ attn,
                  const float* __restrict__ Wg, const float* __restrict__ bg,
                  const float* __restrict__ Wlin, const float* __restrict__ blin,
                  float* __restrict__ coeff) {
    __shared__ floatx4 part[8][64];   // 8 KB
    __shared__ floatx4 dinv4[64];     // 1 KB (256 dinv values)
    const int g = blockIdx.x;
    const int h = g >> 6;
    const int b = g & 63;
    const float* A = attn + ((size_t)(b * Hq + h)) * (Nq * Nq);
    const int tid = threadIdx.x;
    const int rg = tid >> 6;          // 8 row groups of 32 rows
    const int cv = tid & 63;          // float4 column group
    const float* Ap = A + cv * 4;

    floatx4 s1 = (floatx4){0.f, 0.f, 0.f, 0.f};
#pragma unroll 8
    for (int r = 0; r < 32; ++r)
        s1 += *(const floatx4*)(Ap + (size_t)(rg * 32 + r) * 256);
    part[rg][cv] = s1;
    __syncthreads();

    if (tid < 64) {
        floatx4 cs = part[0][tid];
#pragma unroll
        for (int i = 1; i < 8; ++i) cs += part[i][tid];
        floatx4 dv;
#pragma unroll
        for (int i = 0; i < 4; ++i) dv[i] = rsqrtf(cs[i] + 1.0f);
        dinv4[tid] = dv;
    }
    __syncthreads();

    const float* dsc = (const float*)dinv4;
    floatx4 s2 = (floatx4){0.f, 0.f, 0.f, 0.f};
#pragma unroll 8
    for (int r = 0; r < 32; ++r) {
        int rr = rg * 32 + r;
        s2 += dsc[rr] * (*(const floatx4*)(Ap + (size_t)rr * 256));
    }
    part[rg][cv] = s2;
    __syncthreads();

    if (tid < 64) {
        floatx4 ws = part[0][tid];
#pragma unroll
        for (int i = 1; i < 8; ++i) ws += part[i][tid];
        floatx4 dv = dinv4[tid];
        floatx4 sj = (ws + dv) * dv;

        float wr[4], bgl[4];
#pragma unroll
        for (int c = 0; c < 4; ++c) {
            wr[c]  = Wg[0 * 4 + c] + Wg[1 * 4 + c] + Wg[2 * 4 + c] + Wg[3 * 4 + c];
            bgl[c] = bg[c];
        }
        float v[4];
#pragma unroll
        for (int c = 0; c < 4; ++c) {
            v[c] = tanhf(sj[0] * wr[c] + bgl[c]) + tanhf(sj[1] * wr[c] + bgl[c]) +
                   tanhf(sj[2] * wr[c] + bgl[c]) + tanhf(sj[3] * wr[c] + bgl[c]);
#pragma unroll
            for (int o = 32; o >= 1; o >>= 1) v[c] += __shfl_down(v[c], o, 64);
        }
        float g0 = __shfl(v[0], 0, 64), g1 = __shfl(v[1], 0, 64);
        float g2 = __shfl(v[2], 0, 64), g3 = __shfl(v[3], 0, 64);
        if (tid < 4) {
            float r = blin[tid] + (g0 * Wlin[0 * 4 + tid] + g1 * Wlin[1 * 4 + tid] +
                                   g2 * Wlin[2 * 4 + tid] + g3 * Wlin[3 * 4 + tid]) *
                                      (1.0f / 256.0f);
            coeff[g * 4 + tid] = r;
        }
    }
}

// ---------------------------------------------------------------------------
// FUSED Chebyshev recursion + filter (unchanged from r4 — passed, absmax ok).
// ---------------------------------------------------------------------------
__global__ __launch_bounds__(512, 2)
void cheb_fused(const unsigned short* __restrict__ Pb, const float* __restrict__ oeh,
                const float* __restrict__ WchTf, const float* __restrict__ coeff,
                const float* __restrict__ bch, unsigned short* __restrict__ filtb) {
    extern __shared__ unsigned char sm[];
    unsigned short* cm = (unsigned short*)sm;            // [64][256] swizzled, 32 KB
    unsigned short* rm = (unsigned short*)(sm + 32768);  // [256][64] swizzled, 32 KB
    unsigned short* Wl = (unsigned short*)(sm + 65536);  // [64][72], 9 KB

    const int g = blockIdx.x;
    const int b = (g & 7) * 8 + ((g >> 3) & 7);  // XCD-chunked: same b -> same XCD
    const int h = g >> 6;
    const int tid = threadIdx.x;
    const int lane = tid & 63, wv = tid >> 6;
    const int wr = wv >> 1, wc = wv & 1;
    const int quad = lane >> 4, l15 = lane & 15;

    const unsigned short* Pbase = Pb + ((size_t)b << 16);
    const float* cf = coeff + (h * 64 + b) * 4;

    // ---- stage X0 (cm + rm) and W0 ----
    {
        const int sn = tid >> 1;
        const int sh = (tid & 1) * 32;
        const float* sp = oeh + (size_t)(b * 256 + sn) * 512 + h * 64 + sh;
        unsigned int pk[16];
#pragma unroll
        for (int j = 0; j < 8; ++j) {
            float4 v = *(const float4*)(sp + j * 4);
            pk[2 * j]     = (unsigned)f2bf(v.x) | ((unsigned)f2bf(v.y) << 16);
            pk[2 * j + 1] = (unsigned)f2bf(v.z) | ((unsigned)f2bf(v.w) << 16);
        }
#pragma unroll
        for (int jj = 0; jj < 4; ++jj)
            *(uint4*)(rm + sn * 64 + ((((sh >> 3) + jj) ^ (sn & 7)) << 3)) =
                make_uint4(pk[4 * jj], pk[4 * jj + 1], pk[4 * jj + 2], pk[4 * jj + 3]);
#pragma unroll
        for (int e = 0; e < 32; ++e) {
            int c = sh + e;
            unsigned short v =
                (unsigned short)((e & 1) ? (pk[e >> 1] >> 16) : (pk[e >> 1] & 0xffffu));
            cm[c * 256 + (((sn >> 3) ^ (c & 31)) << 3) + (sn & 7)] = v;
        }
        float ck = cf[0];
        int r = tid >> 3, su = tid & 7;
        const float* wp = WchTf + r * 64 + su * 8;
        float4 w0 = *(const float4*)wp, w1 = *(const float4*)(wp + 4);
        *(uint4*)(Wl + r * 72 + su * 8) = make_uint4(
            (unsigned)f2bf(w0.x * ck) | ((unsigned)f2bf(w0.y * ck) << 16),
            (unsigned)f2bf(w0.z * ck) | ((unsigned)f2bf(w0.w * ck) << 16),
            (unsigned)f2bf(w1.x * ck) | ((unsigned)f2bf(w1.y * ck) << 16),
            (unsigned)f2bf(w1.z * ck) | ((unsigned)f2bf(w1.w * ck) << 16));
    }
    __syncthreads();

    // owned T0 elements into regs (packed bf16 pairs over consecutive rows)
    unsigned int curp[4][2][2], prvp[4][2][2];
#pragma unroll
    for (int rt = 0; rt < 4; ++rt)
#pragma unroll
        for (int ct = 0; ct < 2; ++ct)
#pragma unroll
            for (int p = 0; p < 2; ++p) {
                int m = wr * 64 + rt * 16 + quad * 4 + 2 * p;
                int c = wc * 32 + ct * 16 + l15;
                curp[rt][ct][p] = *(const unsigned int*)(cm + c * 256 +
                                                         (((m >> 3) ^ (c & 31)) << 3) + (m & 7));
                prvp[rt][ct][p] = 0u;
            }

    floatx4 accf[4][2];
#pragma unroll
    for (int rt = 0; rt < 4; ++rt)
#pragma unroll
        for (int ct = 0; ct < 2; ++ct) accf[rt][ct] = (floatx4){0.f, 0.f, 0.f, 0.f};

#pragma unroll
    for (int k = 0; k < 4; ++k) {
        // ---- filt_k: accf += T_k(rm) @ (ck*W_k)(Wl) ----
#pragma unroll
        for (int kk = 0; kk < 2; ++kk) {
            short8 af[4], bfw[2];
#pragma unroll
            for (int rt = 0; rt < 4; ++rt) {
                int row = wr * 64 + rt * 16 + l15;
                af[rt] = *(const short8*)(rm + row * 64 + (((kk * 4 + quad) ^ (row & 7)) << 3));
            }
#pragma unroll
            for (int ct = 0; ct < 2; ++ct) {
                int oc = wc * 32 + ct * 16 + l15;
                bfw[ct] = *(const short8*)(Wl + oc * 72 + kk * 32 + quad * 8);
            }
#pragma unroll
            for (int rt = 0; rt < 4; ++rt)
#pragma unroll
                for (int ct = 0; ct < 2; ++ct)
                    accf[rt][ct] = __builtin_amdgcn_mfma_f32_16x16x32_bf16(
                        af[rt], bfw[ct], accf[rt][ct], 0, 0, 0);
        }
        if (k < 3) {
            // ---- prop: accp = P @ T_k  (A from global, B from cm) ----
            floatx4 accp[4][2];
#pragma unroll
            for (int rt = 0; rt < 4; ++rt)
#pragma unroll
                for (int ct = 0; ct < 2; ++ct) accp[rt][ct] = (floatx4){0.f, 0.f, 0.f, 0.f};
#pragma unroll
            for (int kt = 0; kt < 8; ++kt) {
                short8 ap[4], bp[2];
#pragma unroll
                for (int rt = 0; rt < 4; ++rt) {
                    int row = wr * 64 + rt * 16 + l15;
                    ap[rt] = *(const short8*)(Pbase + row * 256 + kt * 32 + quad * 8);
                }
#pragma unroll
                for (int ct = 0; ct < 2; ++ct) {
                    int c = wc * 32 + ct * 16 + l15;
                    bp[ct] = *(const short8*)(cm + c * 256 + (((kt * 4 + quad) ^ (c & 31)) << 3));
                }
#pragma unroll
                for (int rt = 0; rt < 4; ++rt)
#pragma unroll
                    for (int ct = 0; ct < 2; ++ct)
                        accp[rt][ct] = __builtin_amdgcn_mfma_f32_16x16x32_bf16(
                            ap[rt], bp[ct], accp[rt][ct], 0, 0, 0);
            }
            __syncthreads();  // all reads of cm/rm/Wl done
            // ---- write T_{k+1}; rotate regs; stage W_{k+1} ----
#pragma unroll
            for (int rt = 0; rt < 4; ++rt)
#pragma unroll
                for (int ct = 0; ct < 2; ++ct)
#pragma unroll
                    for (int p = 0; p < 2; ++p) {
                        float a0 = accp[rt][ct][2 * p], a1 = accp[rt][ct][2 * p + 1];
                        if (k > 0) {
                            unsigned pv = prvp[rt][ct][p];
                            a0 = 2.0f * a0 - bf2f((unsigned short)(pv & 0xffffu));
                            a1 = 2.0f * a1 - bf2f((unsigned short)(pv >> 16));
                        }
                        unsigned nv = (unsigned)f2bf(a0) | ((unsigned)f2bf(a1) << 16);
                        prvp[rt][ct][p] = curp[rt][ct][p];
                        curp[rt][ct][p] = nv;
                        int m = wr * 64 + rt * 16 + quad * 4 + 2 * p;
                        int c = wc * 32 + ct * 16 + l15;
                        if (k < 2)  // T3 never used as prop B-operand
                            *(unsigned int*)(cm + c * 256 + (((m >> 3) ^ (c & 31)) << 3) +
                                             (m & 7)) = nv;
                        rm[m * 64 + (((c >> 3) ^ (m & 7)) << 3) + (c & 7)] =
                            (unsigned short)(nv & 0xffffu);
                        rm[(m + 1) * 64 + (((c >> 3) ^ ((m + 1) & 7)) << 3) + (c & 7)] =
                            (unsigned short)(nv >> 16);
                    }
            {
                float ck = cf[k + 1];
                int r = tid >> 3, su = tid & 7;
                const float* wp = WchTf + (k + 1) * 4096 + r * 64 + su * 8;
                float4 w0 = *(const float4*)wp, w1 = *(const float4*)(wp + 4);
                *(uint4*)(Wl + r * 72 + su * 8) = make_uint4(
                    (unsigned)f2bf(w0.x * ck) | ((unsigned)f2bf(w0.y * ck) << 16),
                    (unsigned)f2bf(w0.z * ck) | ((unsigned)f2bf(w0.w * ck) << 16),
                    (unsigned)f2bf(w1.x * ck) | ((unsigned)f2bf(w1.y * ck) << 16),
                    (unsigned)f2bf(w1.z * ck) | ((unsigned)f2bf(w1.w * ck) << 16));
            }
            __syncthreads();
        }
    }

    // ---- epilogue: filtb[(n*B+b)*512 + h*64 + c] = bf16(accf + b_cheb) ----
    float bias[2];
#pragma unroll
    for (int ct = 0; ct < 2; ++ct) bias[ct] = bch[wc * 32 + ct * 16 + l15];
#pragma unroll
    for (int rt = 0; rt < 4; ++rt)
#pragma unroll
        for (int ct = 0; ct < 2; ++ct) {
            int c = wc * 32 + ct * 16 + l15;
#pragma unroll
            for (int i = 0; i < 4; ++i) {
                int m = wr * 64 + rt * 16 + quad * 4 + i;
                filtb[((size_t)m * 64 + b) * 512 + h * 64 + c] =
                    f2bf(accf[rt][ct][i] + bias[ct]);
            }
        }
}

// ---------------------------------------------------------------------------
// MFMA GEMM (M=16384, K=1024, N=512) + fused LayerNorm.
// r5: 2-deep A/B load pipeline + raw s_barrier in K-loop (no vmcnt(0) drain) so
// loads stay in flight across barriers; compiler emits counted vmcnt at uses.
// ---------------------------------------------------------------------------
__global__ __launch_bounds__(512, 2)
void gemm_ln_mfma(const float* __restrict__ outp, const unsigned short* __restrict__ filtb,
                  const unsigned short* __restrict__ Wt2, const float* __restrict__ bcat,
                  const float* __restrict__ gamma, const float* __restrict__ beta,
                  float* __restrict__ out) {
    extern __shared__ unsigned char smc[];
    unsigned short* A_lds0 = (unsigned short*)smc;           // 4 KB
    unsigned short* A_lds1 = (unsigned short*)(smc + 4096);  // 4 KB
    float* ep = (float*)smc;                                 // 64 KB epilogue overlay

    const int tid = threadIdx.x;
    const int lane = tid & 63;
    const int wv = tid >> 6;
    const int quad = lane >> 4;
    const int l15 = lane & 15;
    const int r0 = blockIdx.x * 64;

    const int s_row = tid >> 3;
    const int s_sub = tid & 7;
    const int s_q   = s_sub >> 1;
    const int s_e   = (s_sub & 1) * 4;

    const size_t boff = (size_t)(quad * 512 + wv * 64 + l15) * 8;

    floatx4 acc[4][4];
#pragma unroll
    for (int rt = 0; rt < 4; ++rt)
#pragma unroll
        for (int ct = 0; ct < 4; ++ct) acc[rt][ct] = (floatx4){0.f, 0.f, 0.f, 0.f};

    short8 bA[4], bB[4];              // B frags: bA = even kt, bB = odd kt (2-deep)
    float4 avX_f, avY_f;              // A raw (outp source): X = even kt, Y = odd kt
    uint2  avX_b, avY_b;              // A raw (filtb source)

    // Prologue: B(0),B(1); A(0) -> LDS0 direct; issue A(1) -> avY.
    {
#pragma unroll
        for (int ct = 0; ct < 4; ++ct)
            bA[ct] = *(const short8*)(Wt2 + boff + ct * 128);
#pragma unroll
        for (int ct = 0; ct < 4; ++ct)
            bB[ct] = *(const short8*)(Wt2 + (size_t)16384 + boff + ct * 128);
        float4 av = *(const float4*)(outp + (size_t)(r0 + s_row) * 512 + s_sub * 4);
        avY_f = *(const float4*)(outp + (size_t)(r0 + s_row) * 512 + 32 + s_sub * 4);
        uint2 ap;
        ap.x = (unsigned int)f2bf(av.x) | ((unsigned int)f2bf(av.y) << 16);
        ap.y = (unsigned int)f2bf(av.z) | ((unsigned int)f2bf(av.w) << 16);
        *(uint2*)(A_lds0 + (s_q * 64 + s_row) * 8 + s_e) = ap;
        __syncthreads();
    }

// Step KT: issue A(KT+2)->AVN; ds_read A(KT); MFMA w/ BCUR; reload BCUR<-B(KT+2);
// commit A(KT+1) from AVC; lgkm-drain + raw barrier (loads stay in flight).
#define GSTEP(KT, BCUR, AC, AN, AVCF, AVCB, AVNF, AVNB)                             \
    do {                                                                            \
        const int kt_ = (KT);                                                       \
        if (kt_ <= 29) {                                                            \
            const int kc2_ = (kt_ + 2) * 32;                                        \
            if (kc2_ < 512)                                                         \
                AVNF = *(const float4*)(outp + (size_t)(r0 + s_row) * 512 +         \
                                        kc2_ + s_sub * 4);                          \
            else                                                                    \
                AVNB = *(const uint2*)(filtb + (size_t)(r0 + s_row) * 512 +         \
                                       (kc2_ - 512) + s_sub * 4);                   \
        }                                                                           \
        short8 af_[4];                                                              \
        _Pragma("unroll")                                                           \
        for (int rt = 0; rt < 4; ++rt)                                              \
            af_[rt] = *(const short8*)(AC + (quad * 64 + rt * 16 + l15) * 8);       \
        _Pragma("unroll")                                                           \
        for (int rt = 0; rt < 4; ++rt)                                              \
            _Pragma("unroll")                                                       \
            for (int ct = 0; ct < 4; ++ct)                                          \
                acc[rt][ct] = __builtin_amdgcn_mfma_f32_16x16x32_bf16(              \
                    af_[rt], BCUR[ct], acc[rt][ct], 0, 0, 0);                       \
        if (kt_ <= 29) {                                                            \
            _Pragma("unroll")                                                       \
            for (int ct = 0; ct < 4; ++ct)                                          \
                BCUR[ct] = *(const short8*)(Wt2 + (size_t)(kt_ + 2) * 16384 +       \
                                            boff + ct * 128);                       \
        }                                                                           \
        if (kt_ <= 30) {                                                            \
            uint2 ap_;                                                              \
            if ((kt_ + 1) * 32 < 512) {                                             \
                ap_.x = (unsigned int)f2bf(AVCF.x) | ((unsigned int)f2bf(AVCF.y) << 16); \
                ap_.y = (unsigned int)f2bf(AVCF.z) | ((unsigned int)f2bf(AVCF.w) << 16); \
            } else {                                                                \
                ap_ = AVCB;                                                         \
            }                                                                       \
            *(uint2*)(AN + (s_q * 64 + s_row) * 8 + s_e) = ap_;                     \
        }                                                                           \
        asm volatile("s_waitcnt lgkmcnt(0)" ::: "memory");                          \
        __builtin_amdgcn_s_barrier();                                               \
        __builtin_amdgcn_sched_barrier(0);                                          \
    } while (0)

    for (int kt2 = 0; kt2 < 16; ++kt2) {
        GSTEP(2 * kt2,     bA, A_lds0, A_lds1, avY_f, avY_b, avX_f, avX_b);
        GSTEP(2 * kt2 + 1, bB, A_lds1, A_lds0, avX_f, avX_b, avY_f, avY_b);
    }
#undef GSTEP

    float gg[8], bb[8];
#pragma unroll
    for (int i = 0; i < 8; ++i) { gg[i] = gamma[i * 64 + lane]; bb[i] = beta[i * 64 + lane]; }
    float bc[4];
#pragma unroll
    for (int ct = 0; ct < 4; ++ct) bc[ct] = bcat[wv * 64 + ct * 16 + l15];

    for (int half = 0; half < 2; ++half) {
        __syncthreads();
#pragma unroll
        for (int rt2 = 0; rt2 < 2; ++rt2) {
            const int rt = half * 2 + rt2;
#pragma unroll
            for (int ct = 0; ct < 4; ++ct) {
                const int col = wv * 64 + ct * 16 + l15;
#pragma unroll
                for (int i = 0; i < 4; ++i) {
                    const int row_l = rt2 * 16 + quad * 4 + i;
                    ep[row_l * 512 + col] = acc[rt][ct][i] + bc[ct];
                }
            }
        }
        __syncthreads();
#pragma unroll
        for (int m4 = 0; m4 < 4; ++m4) {
            const int m = wv * 4 + m4;
            float s = 0.0f, ss = 0.0f;
#pragma unroll
            for (int i = 0; i < 8; ++i) {
                float v = ep[m * 512 + i * 64 + lane];
                s += v; ss += v * v;
            }
#pragma unroll
            for (int o = 32; o >= 1; o >>= 1) {
                s += __shfl_down(s, o, 64);
                ss += __shfl_down(ss, o, 64);
            }
            s = __shfl(s, 0, 64);
            ss = __shfl(ss, 0, 64);
            const float mu = s * (1.0f / 512.0f);
            const float var = ss * (1.0f / 512.0f) - mu * mu;
            const float rs = rsqrtf(var + 1e-5f);
            const int r = r0 + half * 32 + m;
#pragma unroll
            for (int i = 0; i < 8; ++i) {
                const int d = i * 64 + lane;
                out[(size_t)r * 512 + d] = (ep[m * 512 + d] - mu) * rs * gg[i] + bb[i];
            }
        }
    }
}

// ---------------------------------------------------------------------------
// Launch
// ---------------------------------------------------------------------------
extern "C" void kernel_launch(void* const* d_in, const int* in_sizes, int n_in,
                              void* d_out, int out_size, void* d_ws, size_t ws_size,
                              hipStream_t stream) {
    const float* output       = (const float*)d_in[0];
    const float* attn         = (const float*)d_in[1];
    const float* oeh          = (const float*)d_in[2];
    const int*   edge_index   = (const int*)d_in[3];
    const float* W_gcn        = (const float*)d_in[6];
    const float* b_gcn        = (const float*)d_in[7];
    const float* W_lin        = (const float*)d_in[8];
    const float* b_lin        = (const float*)d_in[9];
    const float* W_cheb       = (const float*)d_in[10];
    const float* b_cheb       = (const float*)d_in[11];
    const float* W_cat        = (const float*)d_in[12];
    const float* b_cat        = (const float*)d_in[13];
    const float* gamma        = (const float*)d_in[14];
    const float* beta         = (const float*)d_in[15];
    float* out = (float*)d_out;

    const int E = in_sizes[3] / 2;
    const int* srcp = edge_index;
    const int* dstp = edge_index + E;

    uint8_t* ws = (uint8_t*)d_ws;
    size_t cur = 0;
    auto alloc = [&](size_t bytes) -> void* {
        void* p = ws + cur;
        cur += (bytes + 255) & ~(size_t)255;
        return p;
    };
    int*   cnt     = (int*)alloc(TOTALq * sizeof(int));
    float* Pf      = (float*)alloc((size_t)64 * 65536 * sizeof(float));     // 16.8 MB
    unsigned short* Pb   = (unsigned short*)alloc((size_t)64 * 65536 * 2);  //  8.4 MB
    float* coeff   = (float*)alloc(512 * 4 * sizeof(float));
    float* WchTf   = (float*)alloc(4 * 64 * 64 * sizeof(float));
    unsigned short* Wt2  = (unsigned short*)alloc((size_t)Dq * 1024 * 2);
    unsigned short* filtb = (unsigned short*)alloc((size_t)TOTALq * Dq * 2);
    (void)ws_size; (void)n_in; (void)out_size;

    hipMemsetAsync(cnt, 0, TOTALq * sizeof(int), stream);
    count_deg_kernel<<<(E + 255) / 256, 256, 0, stream>>>(dstp, cnt, E);
    hipMemsetAsync(Pf, 0, (size_t)64 * 65536 * sizeof(float), stream);
    pscatter_kernel<<<(E + 255) / 256, 256, 0, stream>>>(srcp, dstp, cnt, Pf, E);
    pconv_kernel<<<4096, 256, 0, stream>>>(Pf, Pb);

    coeff_kernel<<<Hq * Bq, 512, 0, stream>>>(attn, W_gcn, b_gcn, W_lin, b_lin, coeff);
    prep_kernel<<<320, 256, 0, stream>>>(W_cat, Wt2, W_cheb, WchTf);

    cheb_fused<<<512, 512, 74752, stream>>>(Pb, oeh, WchTf, coeff, b_cheb, filtb);

    gemm_ln_mfma<<<TOTALq / 64, 512, 65536, stream>>>(output, filtb, Wt2, b_cat,
                                                      gamma, beta, out);
}

// Round 6
// 381.442 us; speedup vs baseline: 1.3068x; 1.0563x over previous
//
#include <hip/hip_runtime.h>
#include <stdint.h>

// Problem constants (fixed by the reference):
#define Bq      64
#define Nq      256
#define Hq      8
#define DHq     64
#define TOTALq  16384    // B*N
#define NTq     131072   // H*TOTAL
#define Dq      512      // H*DH

typedef __attribute__((ext_vector_type(8))) short short8;
typedef __attribute__((ext_vector_type(4))) float floatx4;

__device__ __forceinline__ unsigned short f2bf(float f) {
    union { float f; unsigned int u; } c; c.f = f;
    unsigned int u = c.u;
    return (unsigned short)((u + 0x7fffu + ((u >> 16) & 1u)) >> 16);
}
__device__ __forceinline__ float bf2f(unsigned short u) {
    union { unsigned int u; float f; } c; c.u = ((unsigned int)u) << 16;
    return c.f;
}

// ---------------------------------------------------------------------------
// pscatter: dense per-sample P scatter (dinv folded in; bit-identical).
// ---------------------------------------------------------------------------
__global__ void pscatter_kernel(const int* __restrict__ srcp, const int* __restrict__ dstp,
                                const int* __restrict__ cnt, float* __restrict__ Pf, int E) {
    int e = blockIdx.x * 256 + threadIdx.x;
    if (e >= E) return;
    int s = srcp[e], d = dstp[e];
    int cs = cnt[s], cd = cnt[d];
    float dvs = (cs > 0) ? rsqrtf((float)cs) : 0.0f;
    float dvd = (cd > 0) ? rsqrtf((float)cd) : 0.0f;
    int g = d >> 8;  // sample index
    atomicAdd(&Pf[((size_t)g << 16) + ((size_t)(d & 255) << 8) + (s & 255)],
              -(dvs * dvd));
}

__global__ void pconv_kernel(const float* __restrict__ Pf, unsigned short* __restrict__ Pb) {
    int i = (blockIdx.x * 256 + threadIdx.x) * 4;
    float4 v = *(const float4*)(Pf + i);
    unsigned int lo = (unsigned int)f2bf(v.x) | ((unsigned int)f2bf(v.y) << 16);
    unsigned int hi = (unsigned int)f2bf(v.z) | ((unsigned int)f2bf(v.w) << 16);
    *(uint2*)(Pb + i) = make_uint2(lo, hi);
}

// ---------------------------------------------------------------------------
// Heterogeneous front kernel (512 threads/block). Block roles by range:
//   [0,512):                coeff (single-pass: A slice held in registers)
//   [512,512+nbCnt):        degree count (atomics)
//   [.., +160):             prep (Wt2 fragment reorder + WchTf transpose)
//   [.., +2048):            Pf zero-fill
// Roles are independent; BW-bound coeff overlaps latency-bound count/prep.
// ---------------------------------------------------------------------------
__global__ __launch_bounds__(512, 1)
void front_kernel(const float* __restrict__ attn,
                  const float* __restrict__ Wg, const float* __restrict__ bg,
                  const float* __restrict__ Wlin, const float* __restrict__ blin,
                  float* __restrict__ coeff,
                  const int* __restrict__ dstp, int* __restrict__ cnt, int E,
                  const float* __restrict__ Wcat, unsigned short* __restrict__ Wt2,
                  const float* __restrict__ Wch, float* __restrict__ WchTf,
                  float* __restrict__ Pf) {
    __shared__ floatx4 part[8][64];   // 8 KB
    __shared__ floatx4 dinv4[64];     // 1 KB
    const int bid = blockIdx.x;
    const int tid = threadIdx.x;

    if (bid < 512) {
        // ---------------- coeff (one pass over attn; regs cache the slice) ----
        const int g = bid;
        const int h = g >> 6;
        const int b = g & 63;
        const float* A = attn + ((size_t)(b * Hq + h)) * (Nq * Nq);
        const int rg = tid >> 6;          // 8 row groups of 32 rows
        const int cv = tid & 63;          // float4 column group
        const float* Ap = A + cv * 4;

        floatx4 regs[32];
        floatx4 s1 = (floatx4){0.f, 0.f, 0.f, 0.f};
#pragma unroll
        for (int r = 0; r < 32; ++r) {
            regs[r] = *(const floatx4*)(Ap + (size_t)(rg * 32 + r) * 256);
            s1 += regs[r];
        }
        part[rg][cv] = s1;
        __syncthreads();

        if (tid < 64) {
            floatx4 cs = part[0][tid];
#pragma unroll
            for (int i = 1; i < 8; ++i) cs += part[i][tid];
            floatx4 dv;
#pragma unroll
            for (int i = 0; i < 4; ++i) dv[i] = rsqrtf(cs[i] + 1.0f);
            dinv4[tid] = dv;
        }
        __syncthreads();

        const float* dsc = (const float*)dinv4;
        floatx4 s2 = (floatx4){0.f, 0.f, 0.f, 0.f};
#pragma unroll
        for (int r = 0; r < 32; ++r)
            s2 += dsc[rg * 32 + r] * regs[r];
        part[rg][cv] = s2;
        __syncthreads();

        if (tid < 64) {
            floatx4 ws = part[0][tid];
#pragma unroll
            for (int i = 1; i < 8; ++i) ws += part[i][tid];
            floatx4 dv = dinv4[tid];
            floatx4 sj = (ws + dv) * dv;

            float wr[4], bgl[4];
#pragma unroll
            for (int c = 0; c < 4; ++c) {
                wr[c]  = Wg[0 * 4 + c] + Wg[1 * 4 + c] + Wg[2 * 4 + c] + Wg[3 * 4 + c];
                bgl[c] = bg[c];
            }
            float v[4];
#pragma unroll
            for (int c = 0; c < 4; ++c) {
                v[c] = tanhf(sj[0] * wr[c] + bgl[c]) + tanhf(sj[1] * wr[c] + bgl[c]) +
                       tanhf(sj[2] * wr[c] + bgl[c]) + tanhf(sj[3] * wr[c] + bgl[c]);
#pragma unroll
                for (int o = 32; o >= 1; o >>= 1) v[c] += __shfl_down(v[c], o, 64);
            }
            float g0 = __shfl(v[0], 0, 64), g1 = __shfl(v[1], 0, 64);
            float g2 = __shfl(v[2], 0, 64), g3 = __shfl(v[3], 0, 64);
            if (tid < 4) {
                float r = blin[tid] + (g0 * Wlin[0 * 4 + tid] + g1 * Wlin[1 * 4 + tid] +
                                       g2 * Wlin[2 * 4 + tid] + g3 * Wlin[3 * 4 + tid]) *
                                          (1.0f / 256.0f);
                coeff[g * 4 + tid] = r;
            }
        }
        return;
    }

    const int nbCnt = (E + 511) >> 9;
    if (bid < 512 + nbCnt) {
        // ---------------- degree count ----------------
        int e = (bid - 512) * 512 + tid;
        if (e < E) atomicAdd(&cnt[dstp[e]], 1);
        return;
    }
    if (bid < 512 + nbCnt + 160) {
        // ---------------- prep ----------------
        int pb = bid - 512 - nbCnt;
        if (pb < 128) {
            int idx = pb * 512 + tid;            // 0..65535
            int col = idx & 511;
            int ktq = idx >> 9;                  // 0..127 ; k base = ktq*8
            const float* src = Wcat + (size_t)(ktq * 8) * 512 + col;
            unsigned int pk[4];
#pragma unroll
            for (int q2 = 0; q2 < 4; ++q2) {
                unsigned short a = f2bf(src[(q2 * 2 + 0) * 512]);
                unsigned short b = f2bf(src[(q2 * 2 + 1) * 512]);
                pk[q2] = (unsigned int)a | ((unsigned int)b << 16);
            }
            *(uint4*)(Wt2 + (size_t)idx * 8) = make_uint4(pk[0], pk[1], pk[2], pk[3]);
        } else {
            int idx = (pb - 128) * 512 + tid;    // 0..16383
            int k = idx >> 12, rem = idx & 4095;
            int n = rem >> 6, j = rem & 63;
            WchTf[idx] = Wch[(k << 12) + (j << 6) + n];
        }
        return;
    }
    // ---------------- Pf zero-fill ----------------
    {
        int zb = bid - 512 - nbCnt - 160;        // 0..2047
        size_t i = ((size_t)zb * 512 + tid) * 4; // 4.19M floats total
        *(float4*)(Pf + i) = make_float4(0.f, 0.f, 0.f, 0.f);
    }
}

// ---------------------------------------------------------------------------
// FUSED Chebyshev recursion + filter (unchanged from r5 — passed).
// ---------------------------------------------------------------------------
__global__ __launch_bounds__(512, 2)
void cheb_fused(const unsigned short* __restrict__ Pb, const float* __restrict__ oeh,
                const float* __restrict__ WchTf, const float* __restrict__ coeff,
                const float* __restrict__ bch, unsigned short* __restrict__ filtb) {
    extern __shared__ unsigned char sm[];
    unsigned short* cm = (unsigned short*)sm;            // [64][256] swizzled, 32 KB
    unsigned short* rm = (unsigned short*)(sm + 32768);  // [256][64] swizzled, 32 KB
    unsigned short* Wl = (unsigned short*)(sm + 65536);  // [64][72], 9 KB

    const int g = blockIdx.x;
    const int b = (g & 7) * 8 + ((g >> 3) & 7);  // XCD-chunked: same b -> same XCD
    const int h = g >> 6;
    const int tid = threadIdx.x;
    const int lane = tid & 63, wv = tid >> 6;
    const int wr = wv >> 1, wc = wv & 1;
    const int quad = lane >> 4, l15 = lane & 15;

    const unsigned short* Pbase = Pb + ((size_t)b << 16);
    const float* cf = coeff + (h * 64 + b) * 4;

    // ---- stage X0 (cm + rm) and W0 ----
    {
        const int sn = tid >> 1;
        const int sh = (tid & 1) * 32;
        const float* sp = oeh + (size_t)(b * 256 + sn) * 512 + h * 64 + sh;
        unsigned int pk[16];
#pragma unroll
        for (int j = 0; j < 8; ++j) {
            float4 v = *(const float4*)(sp + j * 4);
            pk[2 * j]     = (unsigned)f2bf(v.x) | ((unsigned)f2bf(v.y) << 16);
            pk[2 * j + 1] = (unsigned)f2bf(v.z) | ((unsigned)f2bf(v.w) << 16);
        }
#pragma unroll
        for (int jj = 0; jj < 4; ++jj)
            *(uint4*)(rm + sn * 64 + ((((sh >> 3) + jj) ^ (sn & 7)) << 3)) =
                make_uint4(pk[4 * jj], pk[4 * jj + 1], pk[4 * jj + 2], pk[4 * jj + 3]);
#pragma unroll
        for (int e = 0; e < 32; ++e) {
            int c = sh + e;
            unsigned short v =
                (unsigned short)((e & 1) ? (pk[e >> 1] >> 16) : (pk[e >> 1] & 0xffffu));
            cm[c * 256 + (((sn >> 3) ^ (c & 31)) << 3) + (sn & 7)] = v;
        }
        float ck = cf[0];
        int r = tid >> 3, su = tid & 7;
        const float* wp = WchTf + r * 64 + su * 8;
        float4 w0 = *(const float4*)wp, w1 = *(const float4*)(wp + 4);
        *(uint4*)(Wl + r * 72 + su * 8) = make_uint4(
            (unsigned)f2bf(w0.x * ck) | ((unsigned)f2bf(w0.y * ck) << 16),
            (unsigned)f2bf(w0.z * ck) | ((unsigned)f2bf(w0.w * ck) << 16),
            (unsigned)f2bf(w1.x * ck) | ((unsigned)f2bf(w1.y * ck) << 16),
            (unsigned)f2bf(w1.z * ck) | ((unsigned)f2bf(w1.w * ck) << 16));
    }
    __syncthreads();

    // owned T0 elements into regs (packed bf16 pairs over consecutive rows)
    unsigned int curp[4][2][2], prvp[4][2][2];
#pragma unroll
    for (int rt = 0; rt < 4; ++rt)
#pragma unroll
        for (int ct = 0; ct < 2; ++ct)
#pragma unroll
            for (int p = 0; p < 2; ++p) {
                int m = wr * 64 + rt * 16 + quad * 4 + 2 * p;
                int c = wc * 32 + ct * 16 + l15;
                curp[rt][ct][p] = *(const unsigned int*)(cm + c * 256 +
                                                         (((m >> 3) ^ (c & 31)) << 3) + (m & 7));
                prvp[rt][ct][p] = 0u;
            }

    floatx4 accf[4][2];
#pragma unroll
    for (int rt = 0; rt < 4; ++rt)
#pragma unroll
        for (int ct = 0; ct < 2; ++ct) accf[rt][ct] = (floatx4){0.f, 0.f, 0.f, 0.f};

#pragma unroll
    for (int k = 0; k < 4; ++k) {
        // ---- filt_k: accf += T_k(rm) @ (ck*W_k)(Wl) ----
#pragma unroll
        for (int kk = 0; kk < 2; ++kk) {
            short8 af[4], bfw[2];
#pragma unroll
            for (int rt = 0; rt < 4; ++rt) {
                int row = wr * 64 + rt * 16 + l15;
                af[rt] = *(const short8*)(rm + row * 64 + (((kk * 4 + quad) ^ (row & 7)) << 3));
            }
#pragma unroll
            for (int ct = 0; ct < 2; ++ct) {
                int oc = wc * 32 + ct * 16 + l15;
                bfw[ct] = *(const short8*)(Wl + oc * 72 + kk * 32 + quad * 8);
            }
#pragma unroll
            for (int rt = 0; rt < 4; ++rt)
#pragma unroll
                for (int ct = 0; ct < 2; ++ct)
                    accf[rt][ct] = __builtin_amdgcn_mfma_f32_16x16x32_bf16(
                        af[rt], bfw[ct], accf[rt][ct], 0, 0, 0);
        }
        if (k < 3) {
            // ---- prop: accp = P @ T_k  (A from global, B from cm) ----
            floatx4 accp[4][2];
#pragma unroll
            for (int rt = 0; rt < 4; ++rt)
#pragma unroll
                for (int ct = 0; ct < 2; ++ct) accp[rt][ct] = (floatx4){0.f, 0.f, 0.f, 0.f};
#pragma unroll
            for (int kt = 0; kt < 8; ++kt) {
                short8 ap[4], bp[2];
#pragma unroll
                for (int rt = 0; rt < 4; ++rt) {
                    int row = wr * 64 + rt * 16 + l15;
                    ap[rt] = *(const short8*)(Pbase + row * 256 + kt * 32 + quad * 8);
                }
#pragma unroll
                for (int ct = 0; ct < 2; ++ct) {
                    int c = wc * 32 + ct * 16 + l15;
                    bp[ct] = *(const short8*)(cm + c * 256 + (((kt * 4 + quad) ^ (c & 31)) << 3));
                }
#pragma unroll
                for (int rt = 0; rt < 4; ++rt)
#pragma unroll
                    for (int ct = 0; ct < 2; ++ct)
                        accp[rt][ct] = __builtin_amdgcn_mfma_f32_16x16x32_bf16(
                            ap[rt], bp[ct], accp[rt][ct], 0, 0, 0);
            }
            __syncthreads();  // all reads of cm/rm/Wl done
            // ---- write T_{k+1}; rotate regs; stage W_{k+1} ----
#pragma unroll
            for (int rt = 0; rt < 4; ++rt)
#pragma unroll
                for (int ct = 0; ct < 2; ++ct)
#pragma unroll
                    for (int p = 0; p < 2; ++p) {
                        float a0 = accp[rt][ct][2 * p], a1 = accp[rt][ct][2 * p + 1];
                        if (k > 0) {
                            unsigned pv = prvp[rt][ct][p];
                            a0 = 2.0f * a0 - bf2f((unsigned short)(pv & 0xffffu));
                            a1 = 2.0f * a1 - bf2f((unsigned short)(pv >> 16));
                        }
                        unsigned nv = (unsigned)f2bf(a0) | ((unsigned)f2bf(a1) << 16);
                        prvp[rt][ct][p] = curp[rt][ct][p];
                        curp[rt][ct][p] = nv;
                        int m = wr * 64 + rt * 16 + quad * 4 + 2 * p;
                        int c = wc * 32 + ct * 16 + l15;
                        if (k < 2)  // T3 never used as prop B-operand
                            *(unsigned int*)(cm + c * 256 + (((m >> 3) ^ (c & 31)) << 3) +
                                             (m & 7)) = nv;
                        rm[m * 64 + (((c >> 3) ^ (m & 7)) << 3) + (c & 7)] =
                            (unsigned short)(nv & 0xffffu);
                        rm[(m + 1) * 64 + (((c >> 3) ^ ((m + 1) & 7)) << 3) + (c & 7)] =
                            (unsigned short)(nv >> 16);
                    }
            {
                float ck = cf[k + 1];
                int r = tid >> 3, su = tid & 7;
                const float* wp = WchTf + (k + 1) * 4096 + r * 64 + su * 8;
                float4 w0 = *(const float4*)wp, w1 = *(const float4*)(wp + 4);
                *(uint4*)(Wl + r * 72 + su * 8) = make_uint4(
                    (unsigned)f2bf(w0.x * ck) | ((unsigned)f2bf(w0.y * ck) << 16),
                    (unsigned)f2bf(w0.z * ck) | ((unsigned)f2bf(w0.w * ck) << 16),
                    (unsigned)f2bf(w1.x * ck) | ((unsigned)f2bf(w1.y * ck) << 16),
                    (unsigned)f2bf(w1.z * ck) | ((unsigned)f2bf(w1.w * ck) << 16));
            }
            __syncthreads();
        }
    }

    // ---- epilogue: filtb[(n*B+b)*512 + h*64 + c] = bf16(accf + b_cheb) ----
    float bias[2];
#pragma unroll
    for (int ct = 0; ct < 2; ++ct) bias[ct] = bch[wc * 32 + ct * 16 + l15];
#pragma unroll
    for (int rt = 0; rt < 4; ++rt)
#pragma unroll
        for (int ct = 0; ct < 2; ++ct) {
            int c = wc * 32 + ct * 16 + l15;
#pragma unroll
            for (int i = 0; i < 4; ++i) {
                int m = wr * 64 + rt * 16 + quad * 4 + i;
                filtb[((size_t)m * 64 + b) * 512 + h * 64 + c] =
                    f2bf(accf[rt][ct][i] + bias[ct]);
            }
        }
}

// ---------------------------------------------------------------------------
// MFMA GEMM (M=16384, K=1024, N=512) + fused LayerNorm (unchanged from r5).
// ---------------------------------------------------------------------------
__global__ __launch_bounds__(512, 2)
void gemm_ln_mfma(const float* __restrict__ outp, const unsigned short* __restrict__ filtb,
                  const unsigned short* __restrict__ Wt2, const float* __restrict__ bcat,
                  const float* __restrict__ gamma, const float* __restrict__ beta,
                  float* __restrict__ out) {
    extern __shared__ unsigned char smc[];
    unsigned short* A_lds0 = (unsigned short*)smc;           // 4 KB
    unsigned short* A_lds1 = (unsigned short*)(smc + 4096);  // 4 KB
    float* ep = (float*)smc;                                 // 64 KB epilogue overlay

    const int tid = threadIdx.x;
    const int lane = tid & 63;
    const int wv = tid >> 6;
    const int quad = lane >> 4;
    const int l15 = lane & 15;
    const int r0 = blockIdx.x * 64;

    const int s_row = tid >> 3;
    const int s_sub = tid & 7;
    const int s_q   = s_sub >> 1;
    const int s_e   = (s_sub & 1) * 4;

    const size_t boff = (size_t)(quad * 512 + wv * 64 + l15) * 8;

    floatx4 acc[4][4];
#pragma unroll
    for (int rt = 0; rt < 4; ++rt)
#pragma unroll
        for (int ct = 0; ct < 4; ++ct) acc[rt][ct] = (floatx4){0.f, 0.f, 0.f, 0.f};

    short8 bA[4], bB[4];              // B frags: bA = even kt, bB = odd kt (2-deep)
    float4 avX_f, avY_f;              // A raw (outp source): X = even kt, Y = odd kt
    uint2  avX_b, avY_b;              // A raw (filtb source)

    // Prologue: B(0),B(1); A(0) -> LDS0 direct; issue A(1) -> avY.
    {
#pragma unroll
        for (int ct = 0; ct < 4; ++ct)
            bA[ct] = *(const short8*)(Wt2 + boff + ct * 128);
#pragma unroll
        for (int ct = 0; ct < 4; ++ct)
            bB[ct] = *(const short8*)(Wt2 + (size_t)16384 + boff + ct * 128);
        float4 av = *(const float4*)(outp + (size_t)(r0 + s_row) * 512 + s_sub * 4);
        avY_f = *(const float4*)(outp + (size_t)(r0 + s_row) * 512 + 32 + s_sub * 4);
        uint2 ap;
        ap.x = (unsigned int)f2bf(av.x) | ((unsigned int)f2bf(av.y) << 16);
        ap.y = (unsigned int)f2bf(av.z) | ((unsigned int)f2bf(av.w) << 16);
        *(uint2*)(A_lds0 + (s_q * 64 + s_row) * 8 + s_e) = ap;
        __syncthreads();
    }

#define GSTEP(KT, BCUR, AC, AN, AVCF, AVCB, AVNF, AVNB)                             \
    do {                                                                            \
        const int kt_ = (KT);                                                       \
        if (kt_ <= 29) {                                                            \
            const int kc2_ = (kt_ + 2) * 32;                                        \
            if (kc2_ < 512)                                                         \
                AVNF = *(const float4*)(outp + (size_t)(r0 + s_row) * 512 +         \
                                        kc2_ + s_sub * 4);                          \
            else                                                                    \
                AVNB = *(const uint2*)(filtb + (size_t)(r0 + s_row) * 512 +         \
                                       (kc2_ - 512) + s_sub * 4);                   \
        }                                                                           \
        short8 af_[4];                                                              \
        _Pragma("unroll")                                                           \
        for (int rt = 0; rt < 4; ++rt)                                              \
            af_[rt] = *(const short8*)(AC + (quad * 64 + rt * 16 + l15) * 8);       \
        _Pragma("unroll")                                                           \
        for (int rt = 0; rt < 4; ++rt)                                              \
            _Pragma("unroll")                                                       \
            for (int ct = 0; ct < 4; ++ct)                                          \
                acc[rt][ct] = __builtin_amdgcn_mfma_f32_16x16x32_bf16(              \
                    af_[rt], BCUR[ct], acc[rt][ct], 0, 0, 0);                       \
        if (kt_ <= 29) {                                                            \
            _Pragma("unroll")                                                       \
            for (int ct = 0; ct < 4; ++ct)                                          \
                BCUR[ct] = *(const short8*)(Wt2 + (size_t)(kt_ + 2) * 16384 +       \
                                            boff + ct * 128);                       \
        }                                                                           \
        if (kt_ <= 30) {                                                            \
            uint2 ap_;                                                              \
            if ((kt_ + 1) * 32 < 512) {                                             \
                ap_.x = (unsigned int)f2bf(AVCF.x) | ((unsigned int)f2bf(AVCF.y) << 16); \
                ap_.y = (unsigned int)f2bf(AVCF.z) | ((unsigned int)f2bf(AVCF.w) << 16); \
            } else {                                                                \
                ap_ = AVCB;                                                         \
            }                                                                       \
            *(uint2*)(AN + (s_q * 64 + s_row) * 8 + s_e) = ap_;                     \
        }                                                                           \
        asm volatile("s_waitcnt lgkmcnt(0)" ::: "memory");                          \
        __builtin_amdgcn_s_barrier();                                               \
        __builtin_amdgcn_sched_barrier(0);                                          \
    } while (0)

    for (int kt2 = 0; kt2 < 16; ++kt2) {
        GSTEP(2 * kt2,     bA, A_lds0, A_lds1, avY_f, avY_b, avX_f, avX_b);
        GSTEP(2 * kt2 + 1, bB, A_lds1, A_lds0, avX_f, avX_b, avY_f, avY_b);
    }
#undef GSTEP

    float gg[8], bb[8];
#pragma unroll
    for (int i = 0; i < 8; ++i) { gg[i] = gamma[i * 64 + lane]; bb[i] = beta[i * 64 + lane]; }
    float bc[4];
#pragma unroll
    for (int ct = 0; ct < 4; ++ct) bc[ct] = bcat[wv * 64 + ct * 16 + l15];

    for (int half = 0; half < 2; ++half) {
        __syncthreads();
#pragma unroll
        for (int rt2 = 0; rt2 < 2; ++rt2) {
            const int rt = half * 2 + rt2;
#pragma unroll
            for (int ct = 0; ct < 4; ++ct) {
                const int col = wv * 64 + ct * 16 + l15;
#pragma unroll
                for (int i = 0; i < 4; ++i) {
                    const int row_l = rt2 * 16 + quad * 4 + i;
                    ep[row_l * 512 + col] = acc[rt][ct][i] + bc[ct];
                }
            }
        }
        __syncthreads();
#pragma unroll
        for (int m4 = 0; m4 < 4; ++m4) {
            const int m = wv * 4 + m4;
            float s = 0.0f, ss = 0.0f;
#pragma unroll
            for (int i = 0; i < 8; ++i) {
                float v = ep[m * 512 + i * 64 + lane];
                s += v; ss += v * v;
            }
#pragma unroll
            for (int o = 32; o >= 1; o >>= 1) {
                s += __shfl_down(s, o, 64);
                ss += __shfl_down(ss, o, 64);
            }
            s = __shfl(s, 0, 64);
            ss = __shfl(ss, 0, 64);
            const float mu = s * (1.0f / 512.0f);
            const float var = ss * (1.0f / 512.0f) - mu * mu;
            const float rs = rsqrtf(var + 1e-5f);
            const int r = r0 + half * 32 + m;
#pragma unroll
            for (int i = 0; i < 8; ++i) {
                const int d = i * 64 + lane;
                out[(size_t)r * 512 + d] = (ep[m * 512 + d] - mu) * rs * gg[i] + bb[i];
            }
        }
    }
}

// ---------------------------------------------------------------------------
// Launch
// ---------------------------------------------------------------------------
extern "C" void kernel_launch(void* const* d_in, const int* in_sizes, int n_in,
                              void* d_out, int out_size, void* d_ws, size_t ws_size,
                              hipStream_t stream) {
    const float* output       = (const float*)d_in[0];
    const float* attn         = (const float*)d_in[1];
    const float* oeh          = (const float*)d_in[2];
    const int*   edge_index   = (const int*)d_in[3];
    const float* W_gcn        = (const float*)d_in[6];
    const float* b_gcn        = (const float*)d_in[7];
    const float* W_lin        = (const float*)d_in[8];
    const float* b_lin        = (const float*)d_in[9];
    const float* W_cheb       = (const float*)d_in[10];
    const float* b_cheb       = (const float*)d_in[11];
    const float* W_cat        = (const float*)d_in[12];
    const float* b_cat        = (const float*)d_in[13];
    const float* gamma        = (const float*)d_in[14];
    const float* beta         = (const float*)d_in[15];
    float* out = (float*)d_out;

    const int E = in_sizes[3] / 2;
    const int* srcp = edge_index;
    const int* dstp = edge_index + E;

    uint8_t* ws = (uint8_t*)d_ws;
    size_t cur = 0;
    auto alloc = [&](size_t bytes) -> void* {
        void* p = ws + cur;
        cur += (bytes + 255) & ~(size_t)255;
        return p;
    };
    int*   cnt     = (int*)alloc(TOTALq * sizeof(int));
    float* Pf      = (float*)alloc((size_t)64 * 65536 * sizeof(float));     // 16.8 MB
    unsigned short* Pb   = (unsigned short*)alloc((size_t)64 * 65536 * 2);  //  8.4 MB
    float* coeff   = (float*)alloc(512 * 4 * sizeof(float));
    float* WchTf   = (float*)alloc(4 * 64 * 64 * sizeof(float));
    unsigned short* Wt2  = (unsigned short*)alloc((size_t)Dq * 1024 * 2);
    unsigned short* filtb = (unsigned short*)alloc((size_t)TOTALq * Dq * 2);
    (void)ws_size; (void)n_in; (void)out_size;

    hipMemsetAsync(cnt, 0, TOTALq * sizeof(int), stream);

    const int nbCnt = (E + 511) / 512;
    const int frontGrid = 512 + nbCnt + 160 + 2048;
    front_kernel<<<frontGrid, 512, 0, stream>>>(attn, W_gcn, b_gcn, W_lin, b_lin, coeff,
                                                dstp, cnt, E, W_cat, Wt2, W_cheb, WchTf,
                                                Pf);

    pscatter_kernel<<<(E + 255) / 256, 256, 0, stream>>>(srcp, dstp, cnt, Pf, E);
    pconv_kernel<<<4096, 256, 0, stream>>>(Pf, Pb);

    cheb_fused<<<512, 512, 74752, stream>>>(Pb, oeh, WchTf, coeff, b_cheb, filtb);

    gemm_ln_mfma<<<TOTALq / 64, 512, 65536, stream>>>(output, filtb, Wt2, b_cat,
                                                      gamma, beta, out);
}